// Round 17
// baseline (9147.874 us; speedup 1.0000x reference)
//
#include <hip/hip_runtime.h>
#include <stdint.h>

#define LAYERS    5
#define INPUT_DIM 512
#define CODE_DIM  2048
#define BATCH     32768
#define KSP       32
#define NCAND     40

typedef __attribute__((ext_vector_type(8))) short bf16x8;
typedef __attribute__((ext_vector_type(4))) float f32x4;

__device__ __forceinline__ unsigned short f2bf(float f) {
    uint32_t u = __float_as_uint(f);
    uint32_t r = (u + 0x7fffu + ((u >> 16) & 1u)) >> 16;   // RNE
    return (unsigned short)r;
}

#define GLOAD_LDS16(dst, src) \
    __builtin_amdgcn_global_load_lds((const __attribute__((address_space(1))) uint32_t*)(src), \
                                     (__attribute__((address_space(3))) uint32_t*)(dst), 16, 0, 0)

// ---------------------------------------------------------------------------
// src [512][2048] f32 -> dst [2048][512] f32  (bit copy; used for Dt and WT)
__global__ __launch_bounds__(256) void transpose_512x2048_kernel(const float* __restrict__ src,
                                                                 float* __restrict__ dst)
{
    __shared__ float tile[32][33];
    const int tx = threadIdx.x;
    const int ty = threadIdx.y;
    const int cb = blockIdx.x * 32;
    const int ib = blockIdx.y * 32;
    #pragma unroll
    for (int j = 0; j < 32; j += 8)
        tile[ty + j][tx] = src[(size_t)(ib + ty + j) * CODE_DIM + cb + tx];
    __syncthreads();
    #pragma unroll
    for (int j = 0; j < 32; j += 8)
        dst[(size_t)(cb + ty + j) * INPUT_DIM + ib + tx] = tile[tx][ty + j];
}

// ---------------------------------------------------------------------------
// src [512][2048] f32 -> dst [2048][512] bf16 (transpose + convert, for screen B)
__global__ __launch_bounds__(256) void wbt_cvt_kernel(const float* __restrict__ src,
                                                      unsigned short* __restrict__ dst)
{
    __shared__ float tile[32][33];
    const int tx = threadIdx.x;
    const int ty = threadIdx.y;
    const int cb = blockIdx.x * 32;
    const int ib = blockIdx.y * 32;
    #pragma unroll
    for (int j = 0; j < 32; j += 8)
        tile[ty + j][tx] = src[(size_t)(ib + ty + j) * CODE_DIM + cb + tx];
    __syncthreads();
    #pragma unroll
    for (int j = 0; j < 32; j += 8)
        dst[(size_t)(cb + ty + j) * INPUT_DIM + ib + tx] = f2bf(tile[tx][ty + j]);
}

// ---------------------------------------------------------------------------
// x f32 [32768*512] -> xb bf16 (8 elems/thread)
__global__ __launch_bounds__(256) void cvt_x_kernel(const float* __restrict__ s,
                                                    unsigned short* __restrict__ d)
{
    const size_t base = ((size_t)blockIdx.x * 256 + threadIdx.x) * 8;
    float4 a = *(const float4*)&s[base];
    float4 b = *(const float4*)&s[base + 4];
    uint4 o;
    o.x = (uint32_t)f2bf(a.x) | ((uint32_t)f2bf(a.y) << 16);
    o.y = (uint32_t)f2bf(a.z) | ((uint32_t)f2bf(a.w) << 16);
    o.z = (uint32_t)f2bf(b.x) | ((uint32_t)f2bf(b.y) << 16);
    o.w = (uint32_t)f2bf(b.z) | ((uint32_t)f2bf(b.w) << 16);
    *(uint4*)&d[base] = o;
}

// ---------------------------------------------------------------------------
// SCREEN: u_s = bf16(x) @ bf16(W)  via MFMA 16x16x32  (+ f32 sparse z@S epilogue).
// Approximate (candidate generation only).  LDS-free: A/B fragments loaded
// straight from global (xb row-major k-contig; WbT n-major k-contig).
// Layout-robust in k: A and B use the SAME assumed k-map (l>>4)*8+i, so any
// common k-bijection gives the identical dot product.  m/n = lane&15 matches
// the HW-verified C/D col map (guide m89).  C/D: col=lane&15, row=(l>>4)*4+q.
// Block: 256 thr = 4 waves; tile 64 rows x 128 cols; wave w: rows r0+w*16.
__global__ __launch_bounds__(256) void screen_kernel(
    const unsigned short* __restrict__ xb, const unsigned short* __restrict__ WbT,
    const float* __restrict__ Sl, const int* __restrict__ zidx,
    const float* __restrict__ zval, float* __restrict__ u)
{
    const int t    = threadIdx.x;
    const int lane = t & 63;
    const int w    = t >> 6;
    const int m16  = lane & 15;
    const int g    = lane >> 4;
    const int c0   = blockIdx.x * 128;
    const int r0   = blockIdx.y * 64;

    f32x4 acc[8];
    #pragma unroll
    for (int ns = 0; ns < 8; ++ns) acc[ns] = (f32x4){0.f, 0.f, 0.f, 0.f};

    const unsigned short* ap = xb + (size_t)(r0 + w * 16 + m16) * INPUT_DIM + g * 8;

    for (int kt = 0; kt < INPUT_DIM; kt += 32) {
        bf16x8 af = *(const bf16x8*)(ap + kt);
        #pragma unroll
        for (int ns = 0; ns < 8; ++ns) {
            const unsigned short* bp =
                WbT + (size_t)(c0 + ns * 16 + m16) * INPUT_DIM + kt + g * 8;
            bf16x8 bf = *(const bf16x8*)bp;
            acc[ns] = __builtin_amdgcn_mfma_f32_16x16x32_bf16(af, bf, acc[ns], 0, 0, 0);
        }
    }

    if (Sl != nullptr) {
        const int colb = c0 + m16;
        #pragma unroll
        for (int q = 0; q < 4; ++q) {
            const int row = r0 + w * 16 + g * 4 + q;
            const int*   ip = zidx + (size_t)row * KSP;
            const float* vp = zval + (size_t)row * KSP;
            float za[8];
            #pragma unroll
            for (int ns = 0; ns < 8; ++ns) za[ns] = 0.f;
            for (int k = 0; k < KSP; ++k) {
                int   j = ip[k];
                float v = vp[k];
                const float* srow = Sl + (size_t)j * CODE_DIM + colb;
                #pragma unroll
                for (int ns = 0; ns < 8; ++ns)
                    za[ns] = fmaf(v, srow[ns * 16], za[ns]);
            }
            #pragma unroll
            for (int ns = 0; ns < 8; ++ns) acc[ns][q] += za[ns];
        }
    }

    #pragma unroll
    for (int ns = 0; ns < 8; ++ns) {
        #pragma unroll
        for (int q = 0; q < 4; ++q) {
            const int row = r0 + w * 16 + g * 4 + q;
            u[(size_t)row * CODE_DIM + c0 + ns * 16 + m16] = acc[ns][q];
        }
    }
}

// ---------------------------------------------------------------------------
// top-NCAND candidate SET by screen |u| (one wave per row; key tree + ballot).
__global__ __launch_bounds__(256) void topk40_kernel(const float* __restrict__ u,
                                                     int* __restrict__ cidx)
{
    const int lane = threadIdx.x & 63;
    const int row  = blockIdx.x * 4 + (threadIdx.x >> 6);
    const float* ur = u + (size_t)row * CODE_DIM;

    uint32_t a[32];
    #pragma unroll
    for (int q = 0; q < 8; ++q) {
        float4 v = *(const float4*)&ur[lane * 32 + q * 4];
        a[q * 4 + 0] = (__float_as_uint(v.x) & 0x7fffffffu) + 1u;
        a[q * 4 + 1] = (__float_as_uint(v.y) & 0x7fffffffu) + 1u;
        a[q * 4 + 2] = (__float_as_uint(v.z) & 0x7fffffffu) + 1u;
        a[q * 4 + 3] = (__float_as_uint(v.w) & 0x7fffffffu) + 1u;
    }

    uint32_t wi = 0xFFFFFFFFu;
    for (int it = 0; it < NCAND; ++it) {
        uint32_t t0[16], t1[8], t2[4], t3[2];
        #pragma unroll
        for (int j = 0; j < 16; ++j) t0[j] = a[2*j]  > a[2*j+1]  ? a[2*j]  : a[2*j+1];
        #pragma unroll
        for (int j = 0; j < 8;  ++j) t1[j] = t0[2*j] > t0[2*j+1] ? t0[2*j] : t0[2*j+1];
        #pragma unroll
        for (int j = 0; j < 4;  ++j) t2[j] = t1[2*j] > t1[2*j+1] ? t1[2*j] : t1[2*j+1];
        #pragma unroll
        for (int j = 0; j < 2;  ++j) t3[j] = t2[2*j] > t2[2*j+1] ? t2[2*j] : t2[2*j+1];
        const uint32_t mloc = t3[0] > t3[1] ? t3[0] : t3[1];

        uint32_t gmax = mloc;
        #pragma unroll
        for (int off = 1; off <= 32; off <<= 1) {
            uint32_t og = __shfl_xor(gmax, off);
            gmax = og > gmax ? og : gmax;
        }

        unsigned long long bal = __ballot(mloc == gmax);
        int owner = __ffsll(bal) - 1;

        int bj = 0;
        #pragma unroll
        for (int j = 31; j >= 0; --j)
            if (a[j] == gmax) bj = j;
        int bjo = __shfl(bj, owner);

        uint32_t gidx = (uint32_t)owner * 32u + (uint32_t)bjo;
        if (lane == it) wi = gidx;

        if (lane == owner) {
            #pragma unroll
            for (int j = 0; j < 32; ++j)
                if (j == bjo) a[j] = 0u;
        }
    }

    if (lane < NCAND) cidx[(size_t)row * NCAND + lane] = (int)wi;
}

// ---------------------------------------------------------------------------
// REFINE: recompute u exactly (np-faithful f32 chain) at the NCAND candidates,
// select exact top-32 (|u| desc, tie -> lower col), write index-sorted.
// Chain is bitwise-identical to the full-gemm path: k=0..511 ascending fmaf
// into one acc; separate zacc over the 32 index-ascending prev-z pairs; u=a+za.
__global__ __launch_bounds__(256) void refine_kernel(
    const float* __restrict__ x, const float* __restrict__ WT,
    const float* __restrict__ Sl, const int* __restrict__ cidx,
    int* __restrict__ zidx, float* __restrict__ zval, int has_sparse)
{
    __shared__ float xs[4][INPUT_DIM];
    __shared__ int   pidx[4][KSP];
    __shared__ float pval[4][KSP];

    const int t    = threadIdx.x;
    const int lane = t & 63;
    const int w    = t >> 6;
    const int row  = blockIdx.x * 4 + w;

    const float* xr = x + (size_t)row * INPUT_DIM;
    #pragma unroll
    for (int i = 0; i < 2; ++i)
        *(float4*)&xs[w][(lane + i * 64) * 4] = *(const float4*)&xr[(lane + i * 64) * 4];
    if (has_sparse && lane < KSP) {
        pidx[w][lane] = zidx[(size_t)row * KSP + lane];   // read BEFORE overwrite
        pval[w][lane] = zval[(size_t)row * KSP + lane];
    }
    __syncthreads();

    int   c = 0x7fffffff;
    float a = 0.f;
    if (lane < NCAND) {
        c = cidx[(size_t)row * NCAND + lane];
        const float* wc = WT + (size_t)c * INPUT_DIM;
        #pragma unroll 8
        for (int kq = 0; kq < INPUT_DIM / 4; ++kq) {       // k strictly ascending
            float4 wv = *(const float4*)&wc[kq * 4];
            float4 xv = *(const float4*)&xs[w][kq * 4];
            a = fmaf(xv.x, wv.x, a);
            a = fmaf(xv.y, wv.y, a);
            a = fmaf(xv.z, wv.z, a);
            a = fmaf(xv.w, wv.w, a);
        }
        if (has_sparse) {
            float za = 0.f;
            #pragma unroll 8
            for (int kk = 0; kk < KSP; ++kk)               // index-ascending pairs
                za = fmaf(pval[w][kk], Sl[(size_t)pidx[w][kk] * CODE_DIM + c], za);
            a = a + za;                                    // single add
        }
    }

    uint32_t key = (lane < NCAND) ? ((__float_as_uint(a) & 0x7fffffffu) + 1u) : 0u;

    uint32_t wi = 0u;
    for (int it = 0; it < KSP; ++it) {
        uint32_t bk = key;
        uint32_t bc = (key != 0u) ? (uint32_t)c : 0x7fffffffu;
        #pragma unroll
        for (int off = 1; off <= 32; off <<= 1) {
            uint32_t ok = (uint32_t)__shfl_xor((int)bk, off);
            uint32_t oc = (uint32_t)__shfl_xor((int)bc, off);
            if (ok > bk || (ok == bk && oc < bc)) { bk = ok; bc = oc; }
        }
        if (lane == it) wi = bc;
        if (key != 0u && (uint32_t)c == bc) key = 0u;      // owner retires
    }

    float va = 0.f;
    #pragma unroll
    for (int m = 0; m < NCAND; ++m) {                      // fetch winner values
        uint32_t cm = (uint32_t)__shfl(c, m);
        float    am = __shfl(a, m);
        if (lane < KSP && wi == cm) va = am;
    }

    int rank = 0;
    #pragma unroll
    for (int m = 0; m < KSP; ++m) {                        // index-sorted write
        uint32_t om = (uint32_t)__shfl((int)wi, m);
        rank += (om < wi) ? 1 : 0;
    }
    if (lane < KSP) {
        zidx[(size_t)row * KSP + rank] = (int)wi;
        zval[(size_t)row * KSP + rank] = va;
    }
}

// ---------------------------------------------------------------------------
// FALLBACK (ws too small): r16 f32 gemm (84 VGPR, spill-free)
__global__ __launch_bounds__(256) void gemm_layer_kernel(
    const float* __restrict__ x, const float* __restrict__ Wl,
    const float* __restrict__ Sl, const int* __restrict__ zidx,
    const float* __restrict__ zval, float* __restrict__ u)
{
    __shared__ float As[32][128 + 4];

    const int t   = threadIdx.x;
    const int c0  = blockIdx.x * 128;
    const int r0  = blockIdx.y * 128;
    const int tm0 = (t >> 4) * 8;
    const int cn  = (t & 15) * 4;

    float acc[8][8];
    #pragma unroll
    for (int i = 0; i < 8; ++i)
        #pragma unroll
        for (int j = 0; j < 8; ++j) acc[i][j] = 0.f;

    for (int kt = 0; kt < INPUT_DIM; kt += 32) {
        #pragma unroll
        for (int i = 0; i < 4; ++i) {
            int f   = t * 4 + i;
            int row = f >> 3, kq = f & 7;
            float4 v = *(const float4*)&x[(size_t)(r0 + row) * INPUT_DIM + kt + kq * 4];
            As[kq * 4 + 0][row] = v.x;
            As[kq * 4 + 1][row] = v.y;
            As[kq * 4 + 2][row] = v.z;
            As[kq * 4 + 3][row] = v.w;
        }
        __syncthreads();
        const float* Wb = Wl + (size_t)kt * CODE_DIM + c0 + cn;
        #pragma unroll 4
        for (int kk = 0; kk < 32; ++kk) {
            float av[8], bv[8];
            *(float4*)&av[0] = *(const float4*)&As[kk][tm0];
            *(float4*)&av[4] = *(const float4*)&As[kk][tm0 + 4];
            const float* brow = Wb + (size_t)kk * CODE_DIM;
            *(float4*)&bv[0] = *(const float4*)&brow[0];
            *(float4*)&bv[4] = *(const float4*)&brow[64];
            #pragma unroll
            for (int i = 0; i < 8; ++i)
                #pragma unroll
                for (int j = 0; j < 8; ++j)
                    acc[i][j] = fmaf(av[i], bv[j], acc[i][j]);
        }
        __syncthreads();
    }

    if (Sl != nullptr) {
        #pragma unroll
        for (int i = 0; i < 8; ++i) {
            const int r = r0 + tm0 + i;
            const int*   ip = zidx + (size_t)r * KSP;
            const float* vp = zval + (size_t)r * KSP;
            float zacc[8];
            #pragma unroll
            for (int j = 0; j < 8; ++j) zacc[j] = 0.f;
            for (int k = 0; k < KSP; ++k) {
                int   j = ip[k];
                float v = vp[k];
                const float* srow = Sl + (size_t)j * CODE_DIM + c0 + cn;
                float4 s0 = *(const float4*)&srow[0];
                float4 s1 = *(const float4*)&srow[64];
                zacc[0] = fmaf(v, s0.x, zacc[0]);
                zacc[1] = fmaf(v, s0.y, zacc[1]);
                zacc[2] = fmaf(v, s0.z, zacc[2]);
                zacc[3] = fmaf(v, s0.w, zacc[3]);
                zacc[4] = fmaf(v, s1.x, zacc[4]);
                zacc[5] = fmaf(v, s1.y, zacc[5]);
                zacc[6] = fmaf(v, s1.z, zacc[6]);
                zacc[7] = fmaf(v, s1.w, zacc[7]);
            }
            #pragma unroll
            for (int j = 0; j < 8; ++j)
                acc[i][j] = acc[i][j] + zacc[j];
        }
    }

    #pragma unroll
    for (int i = 0; i < 8; ++i) {
        float* up = u + (size_t)(r0 + tm0 + i) * CODE_DIM + c0 + cn;
        *(float4*)&up[0]  = make_float4(acc[i][0], acc[i][1], acc[i][2], acc[i][3]);
        *(float4*)&up[64] = make_float4(acc[i][4], acc[i][5], acc[i][6], acc[i][7]);
    }
}

// ---------------------------------------------------------------------------
// FALLBACK top-32 (exact, index-sorted output) — r12 kernel
__global__ __launch_bounds__(256) void topk32_wave_kernel(const float* __restrict__ u,
                                                          int* __restrict__ zidx,
                                                          float* __restrict__ zval)
{
    const int lane = threadIdx.x & 63;
    const int row  = blockIdx.x * 4 + (threadIdx.x >> 6);
    const float* ur = u + (size_t)row * CODE_DIM;

    uint32_t a[32];
    #pragma unroll
    for (int q = 0; q < 8; ++q) {
        float4 v = *(const float4*)&ur[lane * 32 + q * 4];
        a[q * 4 + 0] = (__float_as_uint(v.x) & 0x7fffffffu) + 1u;
        a[q * 4 + 1] = (__float_as_uint(v.y) & 0x7fffffffu) + 1u;
        a[q * 4 + 2] = (__float_as_uint(v.z) & 0x7fffffffu) + 1u;
        a[q * 4 + 3] = (__float_as_uint(v.w) & 0x7fffffffu) + 1u;
    }

    uint32_t wi = 0xFFFFFFFFu;
    for (int it = 0; it < KSP; ++it) {
        uint32_t t0[16], t1[8], t2[4], t3[2];
        #pragma unroll
        for (int j = 0; j < 16; ++j) t0[j] = a[2*j]  > a[2*j+1]  ? a[2*j]  : a[2*j+1];
        #pragma unroll
        for (int j = 0; j < 8;  ++j) t1[j] = t0[2*j] > t0[2*j+1] ? t0[2*j] : t0[2*j+1];
        #pragma unroll
        for (int j = 0; j < 4;  ++j) t2[j] = t1[2*j] > t1[2*j+1] ? t1[2*j] : t1[2*j+1];
        #pragma unroll
        for (int j = 0; j < 2;  ++j) t3[j] = t2[2*j] > t2[2*j+1] ? t2[2*j] : t2[2*j+1];
        const uint32_t mloc = t3[0] > t3[1] ? t3[0] : t3[1];

        uint32_t g = mloc;
        #pragma unroll
        for (int off = 1; off <= 32; off <<= 1) {
            uint32_t og = __shfl_xor(g, off);
            g = og > g ? og : g;
        }
        unsigned long long bal = __ballot(mloc == g);
        int owner = __ffsll(bal) - 1;
        int bj = 0;
        #pragma unroll
        for (int j = 31; j >= 0; --j)
            if (a[j] == g) bj = j;
        int bjo = __shfl(bj, owner);
        uint32_t gidx = (uint32_t)owner * 32u + (uint32_t)bjo;
        if (lane == it) wi = gidx;
        if (lane == owner) {
            #pragma unroll
            for (int j = 0; j < 32; ++j)
                if (j == bjo) a[j] = 0u;
        }
    }

    int rank = 0;
    #pragma unroll
    for (int m = 0; m < 32; ++m) {
        uint32_t om = __shfl(wi, m);
        rank += (om < wi) ? 1 : 0;
    }
    if (lane < KSP) {
        int idx = (int)wi;
        zidx[(size_t)row * KSP + rank] = idx;
        zval[(size_t)row * KSP + rank] = ur[idx];
    }
}

// ---------------------------------------------------------------------------
__global__ __launch_bounds__(256) void zfill_scatter_kernel(const int* __restrict__ zidx,
                                                            const float* __restrict__ zval,
                                                            float* __restrict__ zden)
{
    const int t  = threadIdx.x;
    const int r0 = blockIdx.x * 8;
    float* base = zden + (size_t)r0 * CODE_DIM;
    const float4 zero = make_float4(0.f, 0.f, 0.f, 0.f);
    for (int q = t; q < 8 * CODE_DIM / 4; q += 256)
        *(float4*)&base[q * 4] = zero;
    __syncthreads();
    const int rl = t >> 5, k = t & 31;
    int   idx = zidx[(size_t)(r0 + rl) * KSP + k];
    float v   = zval[(size_t)(r0 + rl) * KSP + k];
    base[(size_t)rl * CODE_DIM + idx] = v;
}

// ---------------------------------------------------------------------------
__global__ __launch_bounds__(128) void recon_kernel(const int* __restrict__ zidx,
                                                    const float* __restrict__ zval,
                                                    const float* __restrict__ Dt,
                                                    float* __restrict__ recon)
{
    const int t   = threadIdx.x;
    const int row = blockIdx.x;
    float4 acc = make_float4(0.f, 0.f, 0.f, 0.f);
    const int*   ip = zidx + (size_t)row * KSP;
    const float* vp = zval + (size_t)row * KSP;
    for (int k = 0; k < KSP; ++k) {
        int   j = ip[k];
        float v = vp[k];
        float4 d = *(const float4*)&Dt[(size_t)j * INPUT_DIM + t * 4];
        acc.x = fmaf(v, d.x, acc.x);
        acc.y = fmaf(v, d.y, acc.y);
        acc.z = fmaf(v, d.z, acc.z);
        acc.w = fmaf(v, d.w, acc.w);
    }
    *(float4*)&recon[(size_t)row * INPUT_DIM + t * 4] = acc;
}

// ---------------------------------------------------------------------------
extern "C" void kernel_launch(void* const* d_in, const int* in_sizes, int n_in,
                              void* d_out, int out_size, void* d_ws, size_t ws_size,
                              hipStream_t stream)
{
    const float* x = (const float*)d_in[0];
    const float* W = (const float*)d_in[1];   // [5][512][2048]
    const float* S = (const float*)d_in[2];   // [5][2048][2048]
    const float* D = (const float*)d_in[3];   // [512][2048]

    float* recon = (float*)d_out;
    float* zden  = (float*)d_out + (size_t)BATCH * INPUT_DIM;  // u scratch, then dense z

    char* p = (char*)d_ws;
    int*            zidx = (int*)p;            p += (size_t)BATCH * KSP * 4;        // 4 MB
    float*          zval = (float*)p;          p += (size_t)BATCH * KSP * 4;        // 4 MB
    float*          Dt   = (float*)p;          p += (size_t)CODE_DIM * INPUT_DIM * 4; // 4 MB
    int*            cidx = (int*)p;            p += (size_t)BATCH * NCAND * 4;      // 5.25 MB
    float*          WT   = (float*)p;          p += (size_t)CODE_DIM * INPUT_DIM * 4; // 4 MB
    unsigned short* WbT  = (unsigned short*)p; p += (size_t)CODE_DIM * INPUT_DIM * 2; // 2 MB
    unsigned short* xb   = (unsigned short*)p; p += (size_t)BATCH * INPUT_DIM * 2;  // 32 MB
    const size_t need = (size_t)(p - (char*)d_ws);
    const bool fast = ws_size >= need;

    transpose_512x2048_kernel<<<dim3(CODE_DIM / 32, INPUT_DIM / 32), dim3(32, 8), 0, stream>>>(D, Dt);

    if (fast) {
        cvt_x_kernel<<<BATCH * INPUT_DIM / (256 * 8), 256, 0, stream>>>(x, xb);
        for (int l = 0; l < LAYERS; ++l) {
            const float* Wl = W + (size_t)l * INPUT_DIM * CODE_DIM;
            const float* Sl = (l == 0) ? nullptr : S + (size_t)l * CODE_DIM * CODE_DIM;
            transpose_512x2048_kernel<<<dim3(CODE_DIM / 32, INPUT_DIM / 32), dim3(32, 8), 0, stream>>>(Wl, WT);
            wbt_cvt_kernel<<<dim3(CODE_DIM / 32, INPUT_DIM / 32), dim3(32, 8), 0, stream>>>(Wl, WbT);
            screen_kernel<<<dim3(CODE_DIM / 128, BATCH / 64), 256, 0, stream>>>(
                xb, WbT, Sl, (l == 0) ? nullptr : zidx, (l == 0) ? nullptr : zval, zden);
            topk40_kernel<<<BATCH / 4, 256, 0, stream>>>(zden, cidx);
            refine_kernel<<<BATCH / 4, 256, 0, stream>>>(
                x, WT, Sl, cidx, zidx, zval, l > 0 ? 1 : 0);
        }
    } else {
        for (int l = 0; l < LAYERS; ++l) {
            const float* Wl = W + (size_t)l * INPUT_DIM * CODE_DIM;
            const float* Sl = (l == 0) ? nullptr : S + (size_t)l * CODE_DIM * CODE_DIM;
            gemm_layer_kernel<<<dim3(CODE_DIM / 128, BATCH / 128), 256, 0, stream>>>(
                x, Wl, Sl, (l == 0) ? nullptr : zidx, (l == 0) ? nullptr : zval, zden);
            topk32_wave_kernel<<<BATCH / 4, 256, 0, stream>>>(zden, zidx, zval);
        }
    }

    zfill_scatter_kernel<<<BATCH / 8, 256, 0, stream>>>(zidx, zval, zden);
    recon_kernel<<<BATCH, 128, 0, stream>>>(zidx, zval, Dt, recon);
}

// Round 18
// 7570.300 us; speedup vs baseline: 1.2084x; 1.2084x over previous
//
#include <hip/hip_runtime.h>
#include <stdint.h>

#define LAYERS    5
#define INPUT_DIM 512
#define CODE_DIM  2048
#define BATCH     32768
#define KSP       32
#define NCAND     40

typedef __attribute__((ext_vector_type(8))) short bf16x8;
typedef __attribute__((ext_vector_type(4))) float f32x4;

__device__ __forceinline__ unsigned short f2bf(float f) {
    uint32_t u = __float_as_uint(f);
    uint32_t r = (u + 0x7fffu + ((u >> 16) & 1u)) >> 16;   // RNE
    return (unsigned short)r;
}

#define GLOAD_LDS16(dst, src) \
    __builtin_amdgcn_global_load_lds((const __attribute__((address_space(1))) uint32_t*)(src), \
                                     (__attribute__((address_space(3))) uint32_t*)(dst), 16, 0, 0)

// ---------------------------------------------------------------------------
// src [512][2048] f32 -> dst [2048][512] f32  (bit copy; used for Dt)
__global__ __launch_bounds__(256) void transpose_512x2048_kernel(const float* __restrict__ src,
                                                                 float* __restrict__ dst)
{
    __shared__ float tile[32][33];
    const int tx = threadIdx.x;
    const int ty = threadIdx.y;
    const int cb = blockIdx.x * 32;
    const int ib = blockIdx.y * 32;
    #pragma unroll
    for (int j = 0; j < 32; j += 8)
        tile[ty + j][tx] = src[(size_t)(ib + ty + j) * CODE_DIM + cb + tx];
    __syncthreads();
    #pragma unroll
    for (int j = 0; j < 32; j += 8)
        dst[(size_t)(cb + ty + j) * INPUT_DIM + ib + tx] = tile[tx][ty + j];
}

// ---------------------------------------------------------------------------
// W [512][2048] f32 -> WT [2048][512] f32 AND WbT [2048][512] bf16 (one pass)
__global__ __launch_bounds__(256) void wt_dual_kernel(const float* __restrict__ src,
                                                      float* __restrict__ wt,
                                                      unsigned short* __restrict__ wbt)
{
    __shared__ float tile[32][33];
    const int tx = threadIdx.x;
    const int ty = threadIdx.y;
    const int cb = blockIdx.x * 32;
    const int ib = blockIdx.y * 32;
    #pragma unroll
    for (int j = 0; j < 32; j += 8)
        tile[ty + j][tx] = src[(size_t)(ib + ty + j) * CODE_DIM + cb + tx];
    __syncthreads();
    #pragma unroll
    for (int j = 0; j < 32; j += 8) {
        float v = tile[tx][ty + j];
        wt [(size_t)(cb + ty + j) * INPUT_DIM + ib + tx] = v;
        wbt[(size_t)(cb + ty + j) * INPUT_DIM + ib + tx] = f2bf(v);
    }
}

// ---------------------------------------------------------------------------
// x f32 [32768*512] -> xb bf16 (8 elems/thread)
__global__ __launch_bounds__(256) void cvt_x_kernel(const float* __restrict__ s,
                                                    unsigned short* __restrict__ d)
{
    const size_t base = ((size_t)blockIdx.x * 256 + threadIdx.x) * 8;
    float4 a = *(const float4*)&s[base];
    float4 b = *(const float4*)&s[base + 4];
    uint4 o;
    o.x = (uint32_t)f2bf(a.x) | ((uint32_t)f2bf(a.y) << 16);
    o.y = (uint32_t)f2bf(a.z) | ((uint32_t)f2bf(a.w) << 16);
    o.z = (uint32_t)f2bf(b.x) | ((uint32_t)f2bf(b.y) << 16);
    o.w = (uint32_t)f2bf(b.z) | ((uint32_t)f2bf(b.w) << 16);
    *(uint4*)&d[base] = o;
}

// ---------------------------------------------------------------------------
// SCREEN v2: u_s = bf16(x) @ bf16(W) via MFMA 16x16x32 (+ f32 sparse z@S
// epilogue).  Tile 128 rows x 128 cols, 4 waves (wave w: rows w*32..w*32+31,
// 2 row-frags), kt step 32.  A and B tiles LDS-staged via global_load_lds
// (zero staging VGPRs; unpadded [128][32] bf16 so the wave-linear dest is
// exact).  Staged bits identical to r17's global reads -> same screen values.
// Fragment maps (validated r17, absmax pass): A/B k-map (lane>>4)*8+i common
// to both operands; m/n = lane&15; C/D col=lane&15, row=(lane>>4)*4+q.
__global__ __launch_bounds__(256) void screen_kernel(
    const unsigned short* __restrict__ xb, const unsigned short* __restrict__ WbT,
    const float* __restrict__ Sl, const int* __restrict__ zidx,
    const float* __restrict__ zval, float* __restrict__ u)
{
    __shared__ unsigned short Ash[128][32];   // 8 KB, gload dest (linear)
    __shared__ unsigned short Bsh[128][32];   // 8 KB, gload dest (linear)

    const int t    = threadIdx.x;
    const int lane = t & 63;
    const int w    = t >> 6;
    const int m16  = lane & 15;
    const int g    = lane >> 4;
    const int c0   = blockIdx.x * 128;
    const int r0   = blockIdx.y * 128;

    // gload staging geometry: each gload16 covers 16 rows (4 lanes/row)
    const int srow = lane >> 2;               // 0..15
    const int spart = (lane & 3) * 8;         // short offset within row

    f32x4 acc[2][8];
    #pragma unroll
    for (int mr = 0; mr < 2; ++mr)
        #pragma unroll
        for (int ns = 0; ns < 8; ++ns) acc[mr][ns] = (f32x4){0.f, 0.f, 0.f, 0.f};

    for (int kt = 0; kt < INPUT_DIM; kt += 32) {
        __syncthreads();   // previous tile consumed before overwrite
        // wave w stages A rows w*32..w*32+31 and B rows w*32..w*32+31
        #pragma unroll
        for (int sub = 0; sub < 2; ++sub) {
            GLOAD_LDS16(&Ash[w * 32 + sub * 16][0],
                        xb + (size_t)(r0 + w * 32 + sub * 16 + srow) * INPUT_DIM + kt + spart);
            GLOAD_LDS16(&Bsh[w * 32 + sub * 16][0],
                        WbT + (size_t)(c0 + w * 32 + sub * 16 + srow) * INPUT_DIM + kt + spart);
        }
        __syncthreads();   // vmcnt+lgkm drained by compiler before barrier

        bf16x8 af0 = *(const bf16x8*)&Ash[w * 32 + m16][g * 8];
        bf16x8 af1 = *(const bf16x8*)&Ash[w * 32 + 16 + m16][g * 8];
        #pragma unroll
        for (int ns = 0; ns < 8; ++ns) {
            bf16x8 bf = *(const bf16x8*)&Bsh[ns * 16 + m16][g * 8];
            acc[0][ns] = __builtin_amdgcn_mfma_f32_16x16x32_bf16(af0, bf, acc[0][ns], 0, 0, 0);
            acc[1][ns] = __builtin_amdgcn_mfma_f32_16x16x32_bf16(af1, bf, acc[1][ns], 0, 0, 0);
        }
    }

    if (Sl != nullptr) {
        const int colb = c0 + m16;
        #pragma unroll
        for (int mr = 0; mr < 2; ++mr) {
            #pragma unroll
            for (int q = 0; q < 4; ++q) {
                const int row = r0 + w * 32 + mr * 16 + g * 4 + q;
                const int*   ip = zidx + (size_t)row * KSP;
                const float* vp = zval + (size_t)row * KSP;
                float za[8];
                #pragma unroll
                for (int ns = 0; ns < 8; ++ns) za[ns] = 0.f;
                for (int k = 0; k < KSP; ++k) {
                    int   j = ip[k];
                    float v = vp[k];
                    const float* srw = Sl + (size_t)j * CODE_DIM + colb;
                    #pragma unroll
                    for (int ns = 0; ns < 8; ++ns)
                        za[ns] = fmaf(v, srw[ns * 16], za[ns]);
                }
                #pragma unroll
                for (int ns = 0; ns < 8; ++ns) acc[mr][ns][q] += za[ns];
            }
        }
    }

    #pragma unroll
    for (int mr = 0; mr < 2; ++mr)
        #pragma unroll
        for (int ns = 0; ns < 8; ++ns)
            #pragma unroll
            for (int q = 0; q < 4; ++q) {
                const int row = r0 + w * 32 + mr * 16 + g * 4 + q;
                u[(size_t)row * CODE_DIM + c0 + ns * 16 + m16] = acc[mr][ns][q];
            }
}

// ---------------------------------------------------------------------------
// top-NCAND candidate SET by screen |u| (one wave per row; key tree + ballot).
__global__ __launch_bounds__(256) void topk40_kernel(const float* __restrict__ u,
                                                     int* __restrict__ cidx)
{
    const int lane = threadIdx.x & 63;
    const int row  = blockIdx.x * 4 + (threadIdx.x >> 6);
    const float* ur = u + (size_t)row * CODE_DIM;

    uint32_t a[32];
    #pragma unroll
    for (int q = 0; q < 8; ++q) {
        float4 v = *(const float4*)&ur[lane * 32 + q * 4];
        a[q * 4 + 0] = (__float_as_uint(v.x) & 0x7fffffffu) + 1u;
        a[q * 4 + 1] = (__float_as_uint(v.y) & 0x7fffffffu) + 1u;
        a[q * 4 + 2] = (__float_as_uint(v.z) & 0x7fffffffu) + 1u;
        a[q * 4 + 3] = (__float_as_uint(v.w) & 0x7fffffffu) + 1u;
    }

    uint32_t wi = 0xFFFFFFFFu;
    for (int it = 0; it < NCAND; ++it) {
        uint32_t t0[16], t1[8], t2[4], t3[2];
        #pragma unroll
        for (int j = 0; j < 16; ++j) t0[j] = a[2*j]  > a[2*j+1]  ? a[2*j]  : a[2*j+1];
        #pragma unroll
        for (int j = 0; j < 8;  ++j) t1[j] = t0[2*j] > t0[2*j+1] ? t0[2*j] : t0[2*j+1];
        #pragma unroll
        for (int j = 0; j < 4;  ++j) t2[j] = t1[2*j] > t1[2*j+1] ? t1[2*j] : t1[2*j+1];
        #pragma unroll
        for (int j = 0; j < 2;  ++j) t3[j] = t2[2*j] > t2[2*j+1] ? t2[2*j] : t2[2*j+1];
        const uint32_t mloc = t3[0] > t3[1] ? t3[0] : t3[1];

        uint32_t gmax = mloc;
        #pragma unroll
        for (int off = 1; off <= 32; off <<= 1) {
            uint32_t og = __shfl_xor(gmax, off);
            gmax = og > gmax ? og : gmax;
        }

        unsigned long long bal = __ballot(mloc == gmax);
        int owner = __ffsll(bal) - 1;

        int bj = 0;
        #pragma unroll
        for (int j = 31; j >= 0; --j)
            if (a[j] == gmax) bj = j;
        int bjo = __shfl(bj, owner);

        uint32_t gidx = (uint32_t)owner * 32u + (uint32_t)bjo;
        if (lane == it) wi = gidx;

        if (lane == owner) {
            #pragma unroll
            for (int j = 0; j < 32; ++j)
                if (j == bjo) a[j] = 0u;
        }
    }

    if (lane < NCAND) cidx[(size_t)row * NCAND + lane] = (int)wi;
}

// ---------------------------------------------------------------------------
// REFINE: recompute u exactly (np-faithful f32 chain) at the NCAND candidates,
// select exact top-32 (|u| desc, tie -> lower col), write index-sorted.
__global__ __launch_bounds__(256) void refine_kernel(
    const float* __restrict__ x, const float* __restrict__ WT,
    const float* __restrict__ Sl, const int* __restrict__ cidx,
    int* __restrict__ zidx, float* __restrict__ zval, int has_sparse)
{
    __shared__ float xs[4][INPUT_DIM];
    __shared__ int   pidx[4][KSP];
    __shared__ float pval[4][KSP];

    const int t    = threadIdx.x;
    const int lane = t & 63;
    const int w    = t >> 6;
    const int row  = blockIdx.x * 4 + w;

    const float* xr = x + (size_t)row * INPUT_DIM;
    #pragma unroll
    for (int i = 0; i < 2; ++i)
        *(float4*)&xs[w][(lane + i * 64) * 4] = *(const float4*)&xr[(lane + i * 64) * 4];
    if (has_sparse && lane < KSP) {
        pidx[w][lane] = zidx[(size_t)row * KSP + lane];   // read BEFORE overwrite
        pval[w][lane] = zval[(size_t)row * KSP + lane];
    }
    __syncthreads();

    int   c = 0x7fffffff;
    float a = 0.f;
    if (lane < NCAND) {
        c = cidx[(size_t)row * NCAND + lane];
        const float* wc = WT + (size_t)c * INPUT_DIM;
        #pragma unroll 8
        for (int kq = 0; kq < INPUT_DIM / 4; ++kq) {       // k strictly ascending
            float4 wv = *(const float4*)&wc[kq * 4];
            float4 xv = *(const float4*)&xs[w][kq * 4];
            a = fmaf(xv.x, wv.x, a);
            a = fmaf(xv.y, wv.y, a);
            a = fmaf(xv.z, wv.z, a);
            a = fmaf(xv.w, wv.w, a);
        }
        if (has_sparse) {
            float za = 0.f;
            #pragma unroll 8
            for (int kk = 0; kk < KSP; ++kk)               // index-ascending pairs
                za = fmaf(pval[w][kk], Sl[(size_t)pidx[w][kk] * CODE_DIM + c], za);
            a = a + za;                                    // single add
        }
    }

    uint32_t key = (lane < NCAND) ? ((__float_as_uint(a) & 0x7fffffffu) + 1u) : 0u;

    uint32_t wi = 0u;
    for (int it = 0; it < KSP; ++it) {
        uint32_t bk = key;
        uint32_t bc = (key != 0u) ? (uint32_t)c : 0x7fffffffu;
        #pragma unroll
        for (int off = 1; off <= 32; off <<= 1) {
            uint32_t ok = (uint32_t)__shfl_xor((int)bk, off);
            uint32_t oc = (uint32_t)__shfl_xor((int)bc, off);
            if (ok > bk || (ok == bk && oc < bc)) { bk = ok; bc = oc; }
        }
        if (lane == it) wi = bc;
        if (key != 0u && (uint32_t)c == bc) key = 0u;      // owner retires
    }

    float va = 0.f;
    #pragma unroll
    for (int m = 0; m < NCAND; ++m) {                      // fetch winner values
        uint32_t cm = (uint32_t)__shfl(c, m);
        float    am = __shfl(a, m);
        if (lane < KSP && wi == cm) va = am;
    }

    int rank = 0;
    #pragma unroll
    for (int m = 0; m < KSP; ++m) {                        // index-sorted write
        uint32_t om = (uint32_t)__shfl((int)wi, m);
        rank += (om < wi) ? 1 : 0;
    }
    if (lane < KSP) {
        zidx[(size_t)row * KSP + rank] = (int)wi;
        zval[(size_t)row * KSP + rank] = va;
    }
}

// ---------------------------------------------------------------------------
// FALLBACK (ws too small): r16 f32 gemm (84 VGPR, spill-free)
__global__ __launch_bounds__(256) void gemm_layer_kernel(
    const float* __restrict__ x, const float* __restrict__ Wl,
    const float* __restrict__ Sl, const int* __restrict__ zidx,
    const float* __restrict__ zval, float* __restrict__ u)
{
    __shared__ float As[32][128 + 4];

    const int t   = threadIdx.x;
    const int c0  = blockIdx.x * 128;
    const int r0  = blockIdx.y * 128;
    const int tm0 = (t >> 4) * 8;
    const int cn  = (t & 15) * 4;

    float acc[8][8];
    #pragma unroll
    for (int i = 0; i < 8; ++i)
        #pragma unroll
        for (int j = 0; j < 8; ++j) acc[i][j] = 0.f;

    for (int kt = 0; kt < INPUT_DIM; kt += 32) {
        #pragma unroll
        for (int i = 0; i < 4; ++i) {
            int f   = t * 4 + i;
            int row = f >> 3, kq = f & 7;
            float4 v = *(const float4*)&x[(size_t)(r0 + row) * INPUT_DIM + kt + kq * 4];
            As[kq * 4 + 0][row] = v.x;
            As[kq * 4 + 1][row] = v.y;
            As[kq * 4 + 2][row] = v.z;
            As[kq * 4 + 3][row] = v.w;
        }
        __syncthreads();
        const float* Wb = Wl + (size_t)kt * CODE_DIM + c0 + cn;
        #pragma unroll 4
        for (int kk = 0; kk < 32; ++kk) {
            float av[8], bv[8];
            *(float4*)&av[0] = *(const float4*)&As[kk][tm0];
            *(float4*)&av[4] = *(const float4*)&As[kk][tm0 + 4];
            const float* brow = Wb + (size_t)kk * CODE_DIM;
            *(float4*)&bv[0] = *(const float4*)&brow[0];
            *(float4*)&bv[4] = *(const float4*)&brow[64];
            #pragma unroll
            for (int i = 0; i < 8; ++i)
                #pragma unroll
                for (int j = 0; j < 8; ++j)
                    acc[i][j] = fmaf(av[i], bv[j], acc[i][j]);
        }
        __syncthreads();
    }

    if (Sl != nullptr) {
        #pragma unroll
        for (int i = 0; i < 8; ++i) {
            const int r = r0 + tm0 + i;
            const int*   ip = zidx + (size_t)r * KSP;
            const float* vp = zval + (size_t)r * KSP;
            float zacc[8];
            #pragma unroll
            for (int j = 0; j < 8; ++j) zacc[j] = 0.f;
            for (int k = 0; k < KSP; ++k) {
                int   j = ip[k];
                float v = vp[k];
                const float* srow = Sl + (size_t)j * CODE_DIM + c0 + cn;
                float4 s0 = *(const float4*)&srow[0];
                float4 s1 = *(const float4*)&srow[64];
                zacc[0] = fmaf(v, s0.x, zacc[0]);
                zacc[1] = fmaf(v, s0.y, zacc[1]);
                zacc[2] = fmaf(v, s0.z, zacc[2]);
                zacc[3] = fmaf(v, s0.w, zacc[3]);
                zacc[4] = fmaf(v, s1.x, zacc[4]);
                zacc[5] = fmaf(v, s1.y, zacc[5]);
                zacc[6] = fmaf(v, s1.z, zacc[6]);
                zacc[7] = fmaf(v, s1.w, zacc[7]);
            }
            #pragma unroll
            for (int j = 0; j < 8; ++j)
                acc[i][j] = acc[i][j] + zacc[j];
        }
    }

    #pragma unroll
    for (int i = 0; i < 8; ++i) {
        float* up = u + (size_t)(r0 + tm0 + i) * CODE_DIM + c0 + cn;
        *(float4*)&up[0]  = make_float4(acc[i][0], acc[i][1], acc[i][2], acc[i][3]);
        *(float4*)&up[64] = make_float4(acc[i][4], acc[i][5], acc[i][6], acc[i][7]);
    }
}

// ---------------------------------------------------------------------------
// FALLBACK top-32 (exact, index-sorted output) — r12 kernel
__global__ __launch_bounds__(256) void topk32_wave_kernel(const float* __restrict__ u,
                                                          int* __restrict__ zidx,
                                                          float* __restrict__ zval)
{
    const int lane = threadIdx.x & 63;
    const int row  = blockIdx.x * 4 + (threadIdx.x >> 6);
    const float* ur = u + (size_t)row * CODE_DIM;

    uint32_t a[32];
    #pragma unroll
    for (int q = 0; q < 8; ++q) {
        float4 v = *(const float4*)&ur[lane * 32 + q * 4];
        a[q * 4 + 0] = (__float_as_uint(v.x) & 0x7fffffffu) + 1u;
        a[q * 4 + 1] = (__float_as_uint(v.y) & 0x7fffffffu) + 1u;
        a[q * 4 + 2] = (__float_as_uint(v.z) & 0x7fffffffu) + 1u;
        a[q * 4 + 3] = (__float_as_uint(v.w) & 0x7fffffffu) + 1u;
    }

    uint32_t wi = 0xFFFFFFFFu;
    for (int it = 0; it < KSP; ++it) {
        uint32_t t0[16], t1[8], t2[4], t3[2];
        #pragma unroll
        for (int j = 0; j < 16; ++j) t0[j] = a[2*j]  > a[2*j+1]  ? a[2*j]  : a[2*j+1];
        #pragma unroll
        for (int j = 0; j < 8;  ++j) t1[j] = t0[2*j] > t0[2*j+1] ? t0[2*j] : t0[2*j+1];
        #pragma unroll
        for (int j = 0; j < 4;  ++j) t2[j] = t1[2*j] > t1[2*j+1] ? t1[2*j] : t1[2*j+1];
        #pragma unroll
        for (int j = 0; j < 2;  ++j) t3[j] = t2[2*j] > t2[2*j+1] ? t2[2*j] : t2[2*j+1];
        const uint32_t mloc = t3[0] > t3[1] ? t3[0] : t3[1];

        uint32_t g = mloc;
        #pragma unroll
        for (int off = 1; off <= 32; off <<= 1) {
            uint32_t og = __shfl_xor(g, off);
            g = og > g ? og : g;
        }
        unsigned long long bal = __ballot(mloc == g);
        int owner = __ffsll(bal) - 1;
        int bj = 0;
        #pragma unroll
        for (int j = 31; j >= 0; --j)
            if (a[j] == g) bj = j;
        int bjo = __shfl(bj, owner);
        uint32_t gidx = (uint32_t)owner * 32u + (uint32_t)bjo;
        if (lane == it) wi = gidx;
        if (lane == owner) {
            #pragma unroll
            for (int j = 0; j < 32; ++j)
                if (j == bjo) a[j] = 0u;
        }
    }

    int rank = 0;
    #pragma unroll
    for (int m = 0; m < 32; ++m) {
        uint32_t om = __shfl(wi, m);
        rank += (om < wi) ? 1 : 0;
    }
    if (lane < KSP) {
        int idx = (int)wi;
        zidx[(size_t)row * KSP + rank] = idx;
        zval[(size_t)row * KSP + rank] = ur[idx];
    }
}

// ---------------------------------------------------------------------------
__global__ __launch_bounds__(256) void zfill_scatter_kernel(const int* __restrict__ zidx,
                                                            const float* __restrict__ zval,
                                                            float* __restrict__ zden)
{
    const int t  = threadIdx.x;
    const int r0 = blockIdx.x * 8;
    float* base = zden + (size_t)r0 * CODE_DIM;
    const float4 zero = make_float4(0.f, 0.f, 0.f, 0.f);
    for (int q = t; q < 8 * CODE_DIM / 4; q += 256)
        *(float4*)&base[q * 4] = zero;
    __syncthreads();
    const int rl = t >> 5, k = t & 31;
    int   idx = zidx[(size_t)(r0 + rl) * KSP + k];
    float v   = zval[(size_t)(r0 + rl) * KSP + k];
    base[(size_t)rl * CODE_DIM + idx] = v;
}

// ---------------------------------------------------------------------------
__global__ __launch_bounds__(128) void recon_kernel(const int* __restrict__ zidx,
                                                    const float* __restrict__ zval,
                                                    const float* __restrict__ Dt,
                                                    float* __restrict__ recon)
{
    const int t   = threadIdx.x;
    const int row = blockIdx.x;
    float4 acc = make_float4(0.f, 0.f, 0.f, 0.f);
    const int*   ip = zidx + (size_t)row * KSP;
    const float* vp = zval + (size_t)row * KSP;
    for (int k = 0; k < KSP; ++k) {
        int   j = ip[k];
        float v = vp[k];
        float4 d = *(const float4*)&Dt[(size_t)j * INPUT_DIM + t * 4];
        acc.x = fmaf(v, d.x, acc.x);
        acc.y = fmaf(v, d.y, acc.y);
        acc.z = fmaf(v, d.z, acc.z);
        acc.w = fmaf(v, d.w, acc.w);
    }
    *(float4*)&recon[(size_t)row * INPUT_DIM + t * 4] = acc;
}

// ---------------------------------------------------------------------------
extern "C" void kernel_launch(void* const* d_in, const int* in_sizes, int n_in,
                              void* d_out, int out_size, void* d_ws, size_t ws_size,
                              hipStream_t stream)
{
    const float* x = (const float*)d_in[0];
    const float* W = (const float*)d_in[1];   // [5][512][2048]
    const float* S = (const float*)d_in[2];   // [5][2048][2048]
    const float* D = (const float*)d_in[3];   // [512][2048]

    float* recon = (float*)d_out;
    float* zden  = (float*)d_out + (size_t)BATCH * INPUT_DIM;  // u scratch, then dense z

    char* p = (char*)d_ws;
    int*            zidx = (int*)p;            p += (size_t)BATCH * KSP * 4;          // 4 MB
    float*          zval = (float*)p;          p += (size_t)BATCH * KSP * 4;          // 4 MB
    float*          Dt   = (float*)p;          p += (size_t)CODE_DIM * INPUT_DIM * 4; // 4 MB
    int*            cidx = (int*)p;            p += (size_t)BATCH * NCAND * 4;        // 5.25 MB
    float*          WT   = (float*)p;          p += (size_t)CODE_DIM * INPUT_DIM * 4; // 4 MB
    unsigned short* WbT  = (unsigned short*)p; p += (size_t)CODE_DIM * INPUT_DIM * 2; // 2 MB
    unsigned short* xb   = (unsigned short*)p; p += (size_t)BATCH * INPUT_DIM * 2;    // 32 MB
    const size_t need = (size_t)(p - (char*)d_ws);
    const bool fast = ws_size >= need;

    transpose_512x2048_kernel<<<dim3(CODE_DIM / 32, INPUT_DIM / 32), dim3(32, 8), 0, stream>>>(D, Dt);

    if (fast) {
        cvt_x_kernel<<<BATCH * INPUT_DIM / (256 * 8), 256, 0, stream>>>(x, xb);
        for (int l = 0; l < LAYERS; ++l) {
            const float* Wl = W + (size_t)l * INPUT_DIM * CODE_DIM;
            const float* Sl = (l == 0) ? nullptr : S + (size_t)l * CODE_DIM * CODE_DIM;
            wt_dual_kernel<<<dim3(CODE_DIM / 32, INPUT_DIM / 32), dim3(32, 8), 0, stream>>>(Wl, WT, WbT);
            screen_kernel<<<dim3(CODE_DIM / 128, BATCH / 128), 256, 0, stream>>>(
                xb, WbT, Sl, (l == 0) ? nullptr : zidx, (l == 0) ? nullptr : zval, zden);
            topk40_kernel<<<BATCH / 4, 256, 0, stream>>>(zden, cidx);
            refine_kernel<<<BATCH / 4, 256, 0, stream>>>(
                x, WT, Sl, cidx, zidx, zval, l > 0 ? 1 : 0);
        }
    } else {
        for (int l = 0; l < LAYERS; ++l) {
            const float* Wl = W + (size_t)l * INPUT_DIM * CODE_DIM;
            const float* Sl = (l == 0) ? nullptr : S + (size_t)l * CODE_DIM * CODE_DIM;
            gemm_layer_kernel<<<dim3(CODE_DIM / 128, BATCH / 128), 256, 0, stream>>>(
                x, Wl, Sl, (l == 0) ? nullptr : zidx, (l == 0) ? nullptr : zval, zden);
            topk32_wave_kernel<<<BATCH / 4, 256, 0, stream>>>(zden, zidx, zval);
        }
    }

    zfill_scatter_kernel<<<BATCH / 8, 256, 0, stream>>>(zidx, zval, zden);
    recon_kernel<<<BATCH, 128, 0, stream>>>(zidx, zval, Dt, recon);
}

// Round 19
// 7367.709 us; speedup vs baseline: 1.2416x; 1.0275x over previous
//
#include <hip/hip_runtime.h>
#include <stdint.h>

#define LAYERS    5
#define INPUT_DIM 512
#define CODE_DIM  2048
#define BATCH     32768
#define KSP       32
#define NCAND     40

typedef __attribute__((ext_vector_type(8))) short bf16x8;
typedef __attribute__((ext_vector_type(4))) float f32x4;

__device__ __forceinline__ unsigned short f2bf(float f) {
    uint32_t u = __float_as_uint(f);
    uint32_t r = (u + 0x7fffu + ((u >> 16) & 1u)) >> 16;   // RNE
    return (unsigned short)r;
}

#define GLOAD_LDS16(dst, src) \
    __builtin_amdgcn_global_load_lds((const __attribute__((address_space(1))) uint32_t*)(src), \
                                     (__attribute__((address_space(3))) uint32_t*)(dst), 16, 0, 0)

// ---------------------------------------------------------------------------
// src [512][2048] f32 -> dst [2048][512] f32  (bit copy; used for Dt)
__global__ __launch_bounds__(256) void transpose_512x2048_kernel(const float* __restrict__ src,
                                                                 float* __restrict__ dst)
{
    __shared__ float tile[32][33];
    const int tx = threadIdx.x;
    const int ty = threadIdx.y;
    const int cb = blockIdx.x * 32;
    const int ib = blockIdx.y * 32;
    #pragma unroll
    for (int j = 0; j < 32; j += 8)
        tile[ty + j][tx] = src[(size_t)(ib + ty + j) * CODE_DIM + cb + tx];
    __syncthreads();
    #pragma unroll
    for (int j = 0; j < 32; j += 8)
        dst[(size_t)(cb + ty + j) * INPUT_DIM + ib + tx] = tile[tx][ty + j];
}

// ---------------------------------------------------------------------------
// W [512][2048] f32 -> WT [2048][512] f32 AND WbT [2048][512] bf16 (one pass)
__global__ __launch_bounds__(256) void wt_dual_kernel(const float* __restrict__ src,
                                                      float* __restrict__ wt,
                                                      unsigned short* __restrict__ wbt)
{
    __shared__ float tile[32][33];
    const int tx = threadIdx.x;
    const int ty = threadIdx.y;
    const int cb = blockIdx.x * 32;
    const int ib = blockIdx.y * 32;
    #pragma unroll
    for (int j = 0; j < 32; j += 8)
        tile[ty + j][tx] = src[(size_t)(ib + ty + j) * CODE_DIM + cb + tx];
    __syncthreads();
    #pragma unroll
    for (int j = 0; j < 32; j += 8) {
        float v = tile[tx][ty + j];
        wt [(size_t)(cb + ty + j) * INPUT_DIM + ib + tx] = v;
        wbt[(size_t)(cb + ty + j) * INPUT_DIM + ib + tx] = f2bf(v);
    }
}

// ---------------------------------------------------------------------------
// x f32 [32768*512] -> xb bf16 (8 elems/thread)
__global__ __launch_bounds__(256) void cvt_x_kernel(const float* __restrict__ s,
                                                    unsigned short* __restrict__ d)
{
    const size_t base = ((size_t)blockIdx.x * 256 + threadIdx.x) * 8;
    float4 a = *(const float4*)&s[base];
    float4 b = *(const float4*)&s[base + 4];
    uint4 o;
    o.x = (uint32_t)f2bf(a.x) | ((uint32_t)f2bf(a.y) << 16);
    o.y = (uint32_t)f2bf(a.z) | ((uint32_t)f2bf(a.w) << 16);
    o.z = (uint32_t)f2bf(b.x) | ((uint32_t)f2bf(b.y) << 16);
    o.w = (uint32_t)f2bf(b.z) | ((uint32_t)f2bf(b.w) << 16);
    *(uint4*)&d[base] = o;
}

// ---------------------------------------------------------------------------
// SCREEN v3: u_s = bf16(x) @ bf16(W) via MFMA 16x16x32 (+ f32 sparse z@S
// epilogue), DOUBLE-BUFFERED LDS with gload-only staging (zero staging VGPRs;
// r15-validated schedule: prefetch(buf^1) -> compute(buf) -> barrier, the
// barrier's vmcnt drain lands the prefetch AFTER compute hides its latency).
// Output stored as bf16 (halves u traffic; selection-set margin ~0.088 >>
// screen+storage error ~6e-3, empirically validated r17/r18).
// Fragment maps (validated r17): common A/B k-map (lane>>4)*8+i; m/n=lane&15;
// C/D col=lane&15, row=(lane>>4)*4+q.
__global__ __launch_bounds__(256) void screen_kernel(
    const unsigned short* __restrict__ xb, const unsigned short* __restrict__ WbT,
    const float* __restrict__ Sl, const int* __restrict__ zidx,
    const float* __restrict__ zval, unsigned short* __restrict__ u)
{
    __shared__ unsigned short Ash[2][128][32];   // 16 KB, gload dest (linear)
    __shared__ unsigned short Bsh[2][128][32];   // 16 KB

    const int t    = threadIdx.x;
    const int lane = t & 63;
    const int w    = t >> 6;
    const int m16  = lane & 15;
    const int g    = lane >> 4;
    const int c0   = blockIdx.x * 128;
    const int r0   = blockIdx.y * 128;

    // gload staging geometry: each gload16 covers 16 rows (4 lanes/row)
    const int srow  = lane >> 2;              // 0..15
    const int spart = (lane & 3) * 8;         // short offset within row

#define GLOAD_T(B, KT)                                                        \
    GLOAD_LDS16(&Ash[B][w * 32][0],                                           \
        xb  + (size_t)(r0 + w * 32 + srow) * INPUT_DIM + (KT) + spart);       \
    GLOAD_LDS16(&Ash[B][w * 32 + 16][0],                                      \
        xb  + (size_t)(r0 + w * 32 + 16 + srow) * INPUT_DIM + (KT) + spart);  \
    GLOAD_LDS16(&Bsh[B][w * 32][0],                                           \
        WbT + (size_t)(c0 + w * 32 + srow) * INPUT_DIM + (KT) + spart);       \
    GLOAD_LDS16(&Bsh[B][w * 32 + 16][0],                                      \
        WbT + (size_t)(c0 + w * 32 + 16 + srow) * INPUT_DIM + (KT) + spart);

#define COMPUTE_T(B)                                                          \
    {                                                                         \
        bf16x8 af0 = *(const bf16x8*)&Ash[B][w * 32 + m16][g * 8];            \
        bf16x8 af1 = *(const bf16x8*)&Ash[B][w * 32 + 16 + m16][g * 8];       \
        _Pragma("unroll")                                                     \
        for (int ns = 0; ns < 8; ++ns) {                                      \
            bf16x8 bfv = *(const bf16x8*)&Bsh[B][ns * 16 + m16][g * 8];       \
            acc[0][ns] = __builtin_amdgcn_mfma_f32_16x16x32_bf16(af0, bfv, acc[0][ns], 0, 0, 0); \
            acc[1][ns] = __builtin_amdgcn_mfma_f32_16x16x32_bf16(af1, bfv, acc[1][ns], 0, 0, 0); \
        }                                                                     \
    }

    f32x4 acc[2][8];
    #pragma unroll
    for (int mr = 0; mr < 2; ++mr)
        #pragma unroll
        for (int ns = 0; ns < 8; ++ns) acc[mr][ns] = (f32x4){0.f, 0.f, 0.f, 0.f};

    GLOAD_T(0, 0);
    __syncthreads();                           // tile 0 landed

    for (int kt = 0; kt < INPUT_DIM; kt += 64) {
        GLOAD_T(1, kt + 32);                   // async prefetch, overlaps compute
        COMPUTE_T(0);
        __syncthreads();                       // compute(0) done + buf1 landed
        if (kt + 64 < INPUT_DIM) {
            GLOAD_T(0, kt + 64);
        }
        COMPUTE_T(1);
        __syncthreads();                       // compute(1) done + buf0 landed
    }

#undef GLOAD_T
#undef COMPUTE_T

    if (Sl != nullptr) {
        const int colb = c0 + m16;
        #pragma unroll
        for (int mr = 0; mr < 2; ++mr) {
            #pragma unroll
            for (int q = 0; q < 4; ++q) {
                const int row = r0 + w * 32 + mr * 16 + g * 4 + q;
                const int*   ip = zidx + (size_t)row * KSP;
                const float* vp = zval + (size_t)row * KSP;
                float za[8];
                #pragma unroll
                for (int ns = 0; ns < 8; ++ns) za[ns] = 0.f;
                for (int k = 0; k < KSP; ++k) {
                    int   j = ip[k];
                    float v = vp[k];
                    const float* srw = Sl + (size_t)j * CODE_DIM + colb;
                    #pragma unroll
                    for (int ns = 0; ns < 8; ++ns)
                        za[ns] = fmaf(v, srw[ns * 16], za[ns]);
                }
                #pragma unroll
                for (int ns = 0; ns < 8; ++ns) acc[mr][ns][q] += za[ns];
            }
        }
    }

    #pragma unroll
    for (int mr = 0; mr < 2; ++mr)
        #pragma unroll
        for (int ns = 0; ns < 8; ++ns)
            #pragma unroll
            for (int q = 0; q < 4; ++q) {
                const int row = r0 + w * 32 + mr * 16 + g * 4 + q;
                u[(size_t)row * CODE_DIM + c0 + ns * 16 + m16] = f2bf(acc[mr][ns][q]);
            }
}

// ---------------------------------------------------------------------------
// top-NCAND candidate SET by |bf16 screen u| (one wave per row).
// Keys: (bf16 bits & 0x7fff)+1 — monotone in |u_s|; 0 = popped sentinel.
__global__ __launch_bounds__(256) void topk40_kernel(const unsigned short* __restrict__ u,
                                                     int* __restrict__ cidx)
{
    const int lane = threadIdx.x & 63;
    const int row  = blockIdx.x * 4 + (threadIdx.x >> 6);
    const unsigned short* ur = u + (size_t)row * CODE_DIM;

    uint32_t a[32];
    #pragma unroll
    for (int q = 0; q < 4; ++q) {
        uint4 v = *(const uint4*)&ur[lane * 32 + q * 8];
        a[q * 8 + 0] = (v.x & 0x7fffu) + 1u;
        a[q * 8 + 1] = ((v.x >> 16) & 0x7fffu) + 1u;
        a[q * 8 + 2] = (v.y & 0x7fffu) + 1u;
        a[q * 8 + 3] = ((v.y >> 16) & 0x7fffu) + 1u;
        a[q * 8 + 4] = (v.z & 0x7fffu) + 1u;
        a[q * 8 + 5] = ((v.z >> 16) & 0x7fffu) + 1u;
        a[q * 8 + 6] = (v.w & 0x7fffu) + 1u;
        a[q * 8 + 7] = ((v.w >> 16) & 0x7fffu) + 1u;
    }

    uint32_t wi = 0xFFFFFFFFu;
    for (int it = 0; it < NCAND; ++it) {
        uint32_t t0[16], t1[8], t2[4], t3[2];
        #pragma unroll
        for (int j = 0; j < 16; ++j) t0[j] = a[2*j]  > a[2*j+1]  ? a[2*j]  : a[2*j+1];
        #pragma unroll
        for (int j = 0; j < 8;  ++j) t1[j] = t0[2*j] > t0[2*j+1] ? t0[2*j] : t0[2*j+1];
        #pragma unroll
        for (int j = 0; j < 4;  ++j) t2[j] = t1[2*j] > t1[2*j+1] ? t1[2*j] : t1[2*j+1];
        #pragma unroll
        for (int j = 0; j < 2;  ++j) t3[j] = t2[2*j] > t2[2*j+1] ? t2[2*j] : t2[2*j+1];
        const uint32_t mloc = t3[0] > t3[1] ? t3[0] : t3[1];

        uint32_t gmax = mloc;
        #pragma unroll
        for (int off = 1; off <= 32; off <<= 1) {
            uint32_t og = __shfl_xor(gmax, off);
            gmax = og > gmax ? og : gmax;
        }

        unsigned long long bal = __ballot(mloc == gmax);
        int owner = __ffsll(bal) - 1;

        int bj = 0;
        #pragma unroll
        for (int j = 31; j >= 0; --j)
            if (a[j] == gmax) bj = j;
        int bjo = __shfl(bj, owner);

        uint32_t gidx = (uint32_t)owner * 32u + (uint32_t)bjo;
        if (lane == it) wi = gidx;

        if (lane == owner) {
            #pragma unroll
            for (int j = 0; j < 32; ++j)
                if (j == bjo) a[j] = 0u;
        }
    }

    if (lane < NCAND) cidx[(size_t)row * NCAND + lane] = (int)wi;
}

// ---------------------------------------------------------------------------
// REFINE: recompute u exactly (np-faithful f32 chain) at the NCAND candidates,
// select exact top-32 (|u| desc, tie -> lower col), write index-sorted.
__global__ __launch_bounds__(256) void refine_kernel(
    const float* __restrict__ x, const float* __restrict__ WT,
    const float* __restrict__ Sl, const int* __restrict__ cidx,
    int* __restrict__ zidx, float* __restrict__ zval, int has_sparse)
{
    __shared__ float xs[4][INPUT_DIM];
    __shared__ int   pidx[4][KSP];
    __shared__ float pval[4][KSP];

    const int t    = threadIdx.x;
    const int lane = t & 63;
    const int w    = t >> 6;
    const int row  = blockIdx.x * 4 + w;

    const float* xr = x + (size_t)row * INPUT_DIM;
    #pragma unroll
    for (int i = 0; i < 2; ++i)
        *(float4*)&xs[w][(lane + i * 64) * 4] = *(const float4*)&xr[(lane + i * 64) * 4];
    if (has_sparse && lane < KSP) {
        pidx[w][lane] = zidx[(size_t)row * KSP + lane];   // read BEFORE overwrite
        pval[w][lane] = zval[(size_t)row * KSP + lane];
    }
    __syncthreads();

    int   c = 0x7fffffff;
    float a = 0.f;
    if (lane < NCAND) {
        c = cidx[(size_t)row * NCAND + lane];
        const float* wc = WT + (size_t)c * INPUT_DIM;
        #pragma unroll 8
        for (int kq = 0; kq < INPUT_DIM / 4; ++kq) {       // k strictly ascending
            float4 wv = *(const float4*)&wc[kq * 4];
            float4 xv = *(const float4*)&xs[w][kq * 4];
            a = fmaf(xv.x, wv.x, a);
            a = fmaf(xv.y, wv.y, a);
            a = fmaf(xv.z, wv.z, a);
            a = fmaf(xv.w, wv.w, a);
        }
        if (has_sparse) {
            float za = 0.f;
            #pragma unroll 8
            for (int kk = 0; kk < KSP; ++kk)               // index-ascending pairs
                za = fmaf(pval[w][kk], Sl[(size_t)pidx[w][kk] * CODE_DIM + c], za);
            a = a + za;                                    // single add
        }
    }

    uint32_t key = (lane < NCAND) ? ((__float_as_uint(a) & 0x7fffffffu) + 1u) : 0u;

    uint32_t wi = 0u;
    for (int it = 0; it < KSP; ++it) {
        uint32_t bk = key;
        uint32_t bc = (key != 0u) ? (uint32_t)c : 0x7fffffffu;
        #pragma unroll
        for (int off = 1; off <= 32; off <<= 1) {
            uint32_t ok = (uint32_t)__shfl_xor((int)bk, off);
            uint32_t oc = (uint32_t)__shfl_xor((int)bc, off);
            if (ok > bk || (ok == bk && oc < bc)) { bk = ok; bc = oc; }
        }
        if (lane == it) wi = bc;
        if (key != 0u && (uint32_t)c == bc) key = 0u;      // owner retires
    }

    float va = 0.f;
    #pragma unroll
    for (int m = 0; m < NCAND; ++m) {                      // fetch winner values
        uint32_t cm = (uint32_t)__shfl(c, m);
        float    am = __shfl(a, m);
        if (lane < KSP && wi == cm) va = am;
    }

    int rank = 0;
    #pragma unroll
    for (int m = 0; m < KSP; ++m) {                        // index-sorted write
        uint32_t om = (uint32_t)__shfl((int)wi, m);
        rank += (om < wi) ? 1 : 0;
    }
    if (lane < KSP) {
        zidx[(size_t)row * KSP + rank] = (int)wi;
        zval[(size_t)row * KSP + rank] = va;
    }
}

// ---------------------------------------------------------------------------
// FALLBACK (ws too small): r16 f32 gemm (84 VGPR, spill-free)
__global__ __launch_bounds__(256) void gemm_layer_kernel(
    const float* __restrict__ x, const float* __restrict__ Wl,
    const float* __restrict__ Sl, const int* __restrict__ zidx,
    const float* __restrict__ zval, float* __restrict__ u)
{
    __shared__ float As[32][128 + 4];

    const int t   = threadIdx.x;
    const int c0  = blockIdx.x * 128;
    const int r0  = blockIdx.y * 128;
    const int tm0 = (t >> 4) * 8;
    const int cn  = (t & 15) * 4;

    float acc[8][8];
    #pragma unroll
    for (int i = 0; i < 8; ++i)
        #pragma unroll
        for (int j = 0; j < 8; ++j) acc[i][j] = 0.f;

    for (int kt = 0; kt < INPUT_DIM; kt += 32) {
        #pragma unroll
        for (int i = 0; i < 4; ++i) {
            int f   = t * 4 + i;
            int row = f >> 3, kq = f & 7;
            float4 v = *(const float4*)&x[(size_t)(r0 + row) * INPUT_DIM + kt + kq * 4];
            As[kq * 4 + 0][row] = v.x;
            As[kq * 4 + 1][row] = v.y;
            As[kq * 4 + 2][row] = v.z;
            As[kq * 4 + 3][row] = v.w;
        }
        __syncthreads();
        const float* Wb = Wl + (size_t)kt * CODE_DIM + c0 + cn;
        #pragma unroll 4
        for (int kk = 0; kk < 32; ++kk) {
            float av[8], bv[8];
            *(float4*)&av[0] = *(const float4*)&As[kk][tm0];
            *(float4*)&av[4] = *(const float4*)&As[kk][tm0 + 4];
            const float* brow = Wb + (size_t)kk * CODE_DIM;
            *(float4*)&bv[0] = *(const float4*)&brow[0];
            *(float4*)&bv[4] = *(const float4*)&brow[64];
            #pragma unroll
            for (int i = 0; i < 8; ++i)
                #pragma unroll
                for (int j = 0; j < 8; ++j)
                    acc[i][j] = fmaf(av[i], bv[j], acc[i][j]);
        }
        __syncthreads();
    }

    if (Sl != nullptr) {
        #pragma unroll
        for (int i = 0; i < 8; ++i) {
            const int r = r0 + tm0 + i;
            const int*   ip = zidx + (size_t)r * KSP;
            const float* vp = zval + (size_t)r * KSP;
            float zacc[8];
            #pragma unroll
            for (int j = 0; j < 8; ++j) zacc[j] = 0.f;
            for (int k = 0; k < KSP; ++k) {
                int   j = ip[k];
                float v = vp[k];
                const float* srow = Sl + (size_t)j * CODE_DIM + c0 + cn;
                float4 s0 = *(const float4*)&srow[0];
                float4 s1 = *(const float4*)&srow[64];
                zacc[0] = fmaf(v, s0.x, zacc[0]);
                zacc[1] = fmaf(v, s0.y, zacc[1]);
                zacc[2] = fmaf(v, s0.z, zacc[2]);
                zacc[3] = fmaf(v, s0.w, zacc[3]);
                zacc[4] = fmaf(v, s1.x, zacc[4]);
                zacc[5] = fmaf(v, s1.y, zacc[5]);
                zacc[6] = fmaf(v, s1.z, zacc[6]);
                zacc[7] = fmaf(v, s1.w, zacc[7]);
            }
            #pragma unroll
            for (int j = 0; j < 8; ++j)
                acc[i][j] = acc[i][j] + zacc[j];
        }
    }

    #pragma unroll
    for (int i = 0; i < 8; ++i) {
        float* up = u + (size_t)(r0 + tm0 + i) * CODE_DIM + c0 + cn;
        *(float4*)&up[0]  = make_float4(acc[i][0], acc[i][1], acc[i][2], acc[i][3]);
        *(float4*)&up[64] = make_float4(acc[i][4], acc[i][5], acc[i][6], acc[i][7]);
    }
}

// ---------------------------------------------------------------------------
// FALLBACK top-32 on f32 u (exact, index-sorted output) — r12 kernel
__global__ __launch_bounds__(256) void topk32_wave_kernel(const float* __restrict__ u,
                                                          int* __restrict__ zidx,
                                                          float* __restrict__ zval)
{
    const int lane = threadIdx.x & 63;
    const int row  = blockIdx.x * 4 + (threadIdx.x >> 6);
    const float* ur = u + (size_t)row * CODE_DIM;

    uint32_t a[32];
    #pragma unroll
    for (int q = 0; q < 8; ++q) {
        float4 v = *(const float4*)&ur[lane * 32 + q * 4];
        a[q * 4 + 0] = (__float_as_uint(v.x) & 0x7fffffffu) + 1u;
        a[q * 4 + 1] = (__float_as_uint(v.y) & 0x7fffffffu) + 1u;
        a[q * 4 + 2] = (__float_as_uint(v.z) & 0x7fffffffu) + 1u;
        a[q * 4 + 3] = (__float_as_uint(v.w) & 0x7fffffffu) + 1u;
    }

    uint32_t wi = 0xFFFFFFFFu;
    for (int it = 0; it < KSP; ++it) {
        uint32_t t0[16], t1[8], t2[4], t3[2];
        #pragma unroll
        for (int j = 0; j < 16; ++j) t0[j] = a[2*j]  > a[2*j+1]  ? a[2*j]  : a[2*j+1];
        #pragma unroll
        for (int j = 0; j < 8;  ++j) t1[j] = t0[2*j] > t0[2*j+1] ? t0[2*j] : t0[2*j+1];
        #pragma unroll
        for (int j = 0; j < 4;  ++j) t2[j] = t1[2*j] > t1[2*j+1] ? t1[2*j] : t1[2*j+1];
        #pragma unroll
        for (int j = 0; j < 2;  ++j) t3[j] = t2[2*j] > t2[2*j+1] ? t2[2*j] : t2[2*j+1];
        const uint32_t mloc = t3[0] > t3[1] ? t3[0] : t3[1];

        uint32_t g = mloc;
        #pragma unroll
        for (int off = 1; off <= 32; off <<= 1) {
            uint32_t og = __shfl_xor(g, off);
            g = og > g ? og : g;
        }
        unsigned long long bal = __ballot(mloc == g);
        int owner = __ffsll(bal) - 1;
        int bj = 0;
        #pragma unroll
        for (int j = 31; j >= 0; --j)
            if (a[j] == g) bj = j;
        int bjo = __shfl(bj, owner);
        uint32_t gidx = (uint32_t)owner * 32u + (uint32_t)bjo;
        if (lane == it) wi = gidx;
        if (lane == owner) {
            #pragma unroll
            for (int j = 0; j < 32; ++j)
                if (j == bjo) a[j] = 0u;
        }
    }

    int rank = 0;
    #pragma unroll
    for (int m = 0; m < 32; ++m) {
        uint32_t om = __shfl(wi, m);
        rank += (om < wi) ? 1 : 0;
    }
    if (lane < KSP) {
        int idx = (int)wi;
        zidx[(size_t)row * KSP + rank] = idx;
        zval[(size_t)row * KSP + rank] = ur[idx];
    }
}

// ---------------------------------------------------------------------------
__global__ __launch_bounds__(256) void zfill_scatter_kernel(const int* __restrict__ zidx,
                                                            const float* __restrict__ zval,
                                                            float* __restrict__ zden)
{
    const int t  = threadIdx.x;
    const int r0 = blockIdx.x * 8;
    float* base = zden + (size_t)r0 * CODE_DIM;
    const float4 zero = make_float4(0.f, 0.f, 0.f, 0.f);
    for (int q = t; q < 8 * CODE_DIM / 4; q += 256)
        *(float4*)&base[q * 4] = zero;
    __syncthreads();
    const int rl = t >> 5, k = t & 31;
    int   idx = zidx[(size_t)(r0 + rl) * KSP + k];
    float v   = zval[(size_t)(r0 + rl) * KSP + k];
    base[(size_t)rl * CODE_DIM + idx] = v;
}

// ---------------------------------------------------------------------------
__global__ __launch_bounds__(128) void recon_kernel(const int* __restrict__ zidx,
                                                    const float* __restrict__ zval,
                                                    const float* __restrict__ Dt,
                                                    float* __restrict__ recon)
{
    const int t   = threadIdx.x;
    const int row = blockIdx.x;
    float4 acc = make_float4(0.f, 0.f, 0.f, 0.f);
    const int*   ip = zidx + (size_t)row * KSP;
    const float* vp = zval + (size_t)row * KSP;
    for (int k = 0; k < KSP; ++k) {
        int   j = ip[k];
        float v = vp[k];
        float4 d = *(const float4*)&Dt[(size_t)j * INPUT_DIM + t * 4];
        acc.x = fmaf(v, d.x, acc.x);
        acc.y = fmaf(v, d.y, acc.y);
        acc.z = fmaf(v, d.z, acc.z);
        acc.w = fmaf(v, d.w, acc.w);
    }
    *(float4*)&recon[(size_t)row * INPUT_DIM + t * 4] = acc;
}

// ---------------------------------------------------------------------------
extern "C" void kernel_launch(void* const* d_in, const int* in_sizes, int n_in,
                              void* d_out, int out_size, void* d_ws, size_t ws_size,
                              hipStream_t stream)
{
    const float* x = (const float*)d_in[0];
    const float* W = (const float*)d_in[1];   // [5][512][2048]
    const float* S = (const float*)d_in[2];   // [5][2048][2048]
    const float* D = (const float*)d_in[3];   // [512][2048]

    float* recon = (float*)d_out;
    float* zden  = (float*)d_out + (size_t)BATCH * INPUT_DIM;  // u scratch, then dense z
    unsigned short* ub = (unsigned short*)zden;                // bf16 u view (fast path)

    char* p = (char*)d_ws;
    int*            zidx = (int*)p;            p += (size_t)BATCH * KSP * 4;          // 4 MB
    float*          zval = (float*)p;          p += (size_t)BATCH * KSP * 4;          // 4 MB
    float*          Dt   = (float*)p;          p += (size_t)CODE_DIM * INPUT_DIM * 4; // 4 MB
    int*            cidx = (int*)p;            p += (size_t)BATCH * NCAND * 4;        // 5.25 MB
    float*          WT   = (float*)p;          p += (size_t)CODE_DIM * INPUT_DIM * 4; // 4 MB
    unsigned short* WbT  = (unsigned short*)p; p += (size_t)CODE_DIM * INPUT_DIM * 2; // 2 MB
    unsigned short* xb   = (unsigned short*)p; p += (size_t)BATCH * INPUT_DIM * 2;    // 32 MB
    const size_t need = (size_t)(p - (char*)d_ws);
    const bool fast = ws_size >= need;

    transpose_512x2048_kernel<<<dim3(CODE_DIM / 32, INPUT_DIM / 32), dim3(32, 8), 0, stream>>>(D, Dt);

    if (fast) {
        cvt_x_kernel<<<BATCH * INPUT_DIM / (256 * 8), 256, 0, stream>>>(x, xb);
        for (int l = 0; l < LAYERS; ++l) {
            const float* Wl = W + (size_t)l * INPUT_DIM * CODE_DIM;
            const float* Sl = (l == 0) ? nullptr : S + (size_t)l * CODE_DIM * CODE_DIM;
            wt_dual_kernel<<<dim3(CODE_DIM / 32, INPUT_DIM / 32), dim3(32, 8), 0, stream>>>(Wl, WT, WbT);
            screen_kernel<<<dim3(CODE_DIM / 128, BATCH / 128), 256, 0, stream>>>(
                xb, WbT, Sl, (l == 0) ? nullptr : zidx, (l == 0) ? nullptr : zval, ub);
            topk40_kernel<<<BATCH / 4, 256, 0, stream>>>(ub, cidx);
            refine_kernel<<<BATCH / 4, 256, 0, stream>>>(
                x, WT, Sl, cidx, zidx, zval, l > 0 ? 1 : 0);
        }
    } else {
        for (int l = 0; l < LAYERS; ++l) {
            const float* Wl = W + (size_t)l * INPUT_DIM * CODE_DIM;
            const float* Sl = (l == 0) ? nullptr : S + (size_t)l * CODE_DIM * CODE_DIM;
            gemm_layer_kernel<<<dim3(CODE_DIM / 128, BATCH / 128), 256, 0, stream>>>(
                x, Wl, Sl, (l == 0) ? nullptr : zidx, (l == 0) ? nullptr : zval, zden);
            topk32_wave_kernel<<<BATCH / 4, 256, 0, stream>>>(zden, zidx, zval);
        }
    }

    zfill_scatter_kernel<<<BATCH / 8, 256, 0, stream>>>(zidx, zval, zden);
    recon_kernel<<<BATCH, 128, 0, stream>>>(zidx, zval, Dt, recon);
}

// Round 20
// 6534.527 us; speedup vs baseline: 1.3999x; 1.1275x over previous
//
#include <hip/hip_runtime.h>
#include <stdint.h>

#define LAYERS    5
#define INPUT_DIM 512
#define CODE_DIM  2048
#define BATCH     32768
#define KSP       32
#define NCAND     40

typedef __attribute__((ext_vector_type(8))) short bf16x8;
typedef __attribute__((ext_vector_type(4))) float f32x4;

__device__ __forceinline__ unsigned short f2bf(float f) {
    uint32_t u = __float_as_uint(f);
    uint32_t r = (u + 0x7fffu + ((u >> 16) & 1u)) >> 16;   // RNE
    return (unsigned short)r;
}

// za region select: rows [0,16384) -> zaA, [16384,24576) -> zaB, rest -> zaC
__device__ __forceinline__ float* za_row(float* zaA, float* zaB, float* zaC, int row) {
    return (row < 16384) ? zaA + (size_t)row * CODE_DIM
         : (row < 24576) ? zaB + (size_t)(row - 16384) * CODE_DIM
                         : zaC + (size_t)(row - 24576) * CODE_DIM;
}

#define GLOAD_LDS16(dst, src) \
    __builtin_amdgcn_global_load_lds((const __attribute__((address_space(1))) uint32_t*)(src), \
                                     (__attribute__((address_space(3))) uint32_t*)(dst), 16, 0, 0)

// ---------------------------------------------------------------------------
// src [512][2048] f32 -> dst [2048][512] f32  (bit copy; used for Dt)
__global__ __launch_bounds__(256) void transpose_512x2048_kernel(const float* __restrict__ src,
                                                                 float* __restrict__ dst)
{
    __shared__ float tile[32][33];
    const int tx = threadIdx.x;
    const int ty = threadIdx.y;
    const int cb = blockIdx.x * 32;
    const int ib = blockIdx.y * 32;
    #pragma unroll
    for (int j = 0; j < 32; j += 8)
        tile[ty + j][tx] = src[(size_t)(ib + ty + j) * CODE_DIM + cb + tx];
    __syncthreads();
    #pragma unroll
    for (int j = 0; j < 32; j += 8)
        dst[(size_t)(cb + ty + j) * INPUT_DIM + ib + tx] = tile[tx][ty + j];
}

// ---------------------------------------------------------------------------
// W [512][2048] f32 -> WT [2048][512] f32 AND WbT [2048][512] bf16 (one pass)
__global__ __launch_bounds__(256) void wt_dual_kernel(const float* __restrict__ src,
                                                      float* __restrict__ wt,
                                                      unsigned short* __restrict__ wbt)
{
    __shared__ float tile[32][33];
    const int tx = threadIdx.x;
    const int ty = threadIdx.y;
    const int cb = blockIdx.x * 32;
    const int ib = blockIdx.y * 32;
    #pragma unroll
    for (int j = 0; j < 32; j += 8)
        tile[ty + j][tx] = src[(size_t)(ib + ty + j) * CODE_DIM + cb + tx];
    __syncthreads();
    #pragma unroll
    for (int j = 0; j < 32; j += 8) {
        float v = tile[tx][ty + j];
        wt [(size_t)(cb + ty + j) * INPUT_DIM + ib + tx] = v;
        wbt[(size_t)(cb + ty + j) * INPUT_DIM + ib + tx] = f2bf(v);
    }
}

// ---------------------------------------------------------------------------
// x f32 [32768*512] -> xb bf16 (8 elems/thread)
__global__ __launch_bounds__(256) void cvt_x_kernel(const float* __restrict__ s,
                                                    unsigned short* __restrict__ d)
{
    const size_t base = ((size_t)blockIdx.x * 256 + threadIdx.x) * 8;
    float4 a = *(const float4*)&s[base];
    float4 b = *(const float4*)&s[base + 4];
    uint4 o;
    o.x = (uint32_t)f2bf(a.x) | ((uint32_t)f2bf(a.y) << 16);
    o.y = (uint32_t)f2bf(a.z) | ((uint32_t)f2bf(a.w) << 16);
    o.z = (uint32_t)f2bf(b.x) | ((uint32_t)f2bf(b.y) << 16);
    o.w = (uint32_t)f2bf(b.z) | ((uint32_t)f2bf(b.w) << 16);
    *(uint4*)&d[base] = o;
}

// ---------------------------------------------------------------------------
// SCREEN v4: u_s = bf16(x)@bf16(W) via MFMA (+ exact f32 z@S epilogue).
// Double-buffered gload-only LDS staging (r15/r18-validated schedule).
// NEW: when store_za != 0, the EXACT f32 za term (contract chain: zero-init,
// ascending-index fold, exact f32 S and zval) is stored densely so refine
// can skip its 2.7 GB/layer random S-gather.
// Fragment maps validated r17 (absmax bit-match with full-f32 path).
__global__ __launch_bounds__(256) void screen_kernel(
    const unsigned short* __restrict__ xb, const unsigned short* __restrict__ WbT,
    const float* __restrict__ Sl, const int* __restrict__ zidx,
    const float* __restrict__ zval, unsigned short* __restrict__ u,
    float* zaA, float* zaB, float* zaC, int store_za)
{
    __shared__ unsigned short Ash[2][128][32];   // 16 KB, gload dest (linear)
    __shared__ unsigned short Bsh[2][128][32];   // 16 KB

    const int t    = threadIdx.x;
    const int lane = t & 63;
    const int w    = t >> 6;
    const int m16  = lane & 15;
    const int g    = lane >> 4;
    const int c0   = blockIdx.x * 128;
    const int r0   = blockIdx.y * 128;

    const int srow  = lane >> 2;              // 0..15
    const int spart = (lane & 3) * 8;         // short offset within row

#define GLOAD_T(B, KT)                                                        \
    GLOAD_LDS16(&Ash[B][w * 32][0],                                           \
        xb  + (size_t)(r0 + w * 32 + srow) * INPUT_DIM + (KT) + spart);       \
    GLOAD_LDS16(&Ash[B][w * 32 + 16][0],                                      \
        xb  + (size_t)(r0 + w * 32 + 16 + srow) * INPUT_DIM + (KT) + spart);  \
    GLOAD_LDS16(&Bsh[B][w * 32][0],                                           \
        WbT + (size_t)(c0 + w * 32 + srow) * INPUT_DIM + (KT) + spart);       \
    GLOAD_LDS16(&Bsh[B][w * 32 + 16][0],                                      \
        WbT + (size_t)(c0 + w * 32 + 16 + srow) * INPUT_DIM + (KT) + spart);

#define COMPUTE_T(B)                                                          \
    {                                                                         \
        bf16x8 af0 = *(const bf16x8*)&Ash[B][w * 32 + m16][g * 8];            \
        bf16x8 af1 = *(const bf16x8*)&Ash[B][w * 32 + 16 + m16][g * 8];       \
        _Pragma("unroll")                                                     \
        for (int ns = 0; ns < 8; ++ns) {                                      \
            bf16x8 bfv = *(const bf16x8*)&Bsh[B][ns * 16 + m16][g * 8];       \
            acc[0][ns] = __builtin_amdgcn_mfma_f32_16x16x32_bf16(af0, bfv, acc[0][ns], 0, 0, 0); \
            acc[1][ns] = __builtin_amdgcn_mfma_f32_16x16x32_bf16(af1, bfv, acc[1][ns], 0, 0, 0); \
        }                                                                     \
    }

    f32x4 acc[2][8];
    #pragma unroll
    for (int mr = 0; mr < 2; ++mr)
        #pragma unroll
        for (int ns = 0; ns < 8; ++ns) acc[mr][ns] = (f32x4){0.f, 0.f, 0.f, 0.f};

    GLOAD_T(0, 0);
    __syncthreads();

    for (int kt = 0; kt < INPUT_DIM; kt += 64) {
        GLOAD_T(1, kt + 32);
        COMPUTE_T(0);
        __syncthreads();
        if (kt + 64 < INPUT_DIM) {
            GLOAD_T(0, kt + 64);
        }
        COMPUTE_T(1);
        __syncthreads();
    }

#undef GLOAD_T
#undef COMPUTE_T

    if (Sl != nullptr) {
        const int colb = c0 + m16;
        #pragma unroll
        for (int mr = 0; mr < 2; ++mr) {
            #pragma unroll
            for (int q = 0; q < 4; ++q) {
                const int row = r0 + w * 32 + mr * 16 + g * 4 + q;
                const int*   ip = zidx + (size_t)row * KSP;
                const float* vp = zval + (size_t)row * KSP;
                float za[8];
                #pragma unroll
                for (int ns = 0; ns < 8; ++ns) za[ns] = 0.f;
                for (int k = 0; k < KSP; ++k) {          // ascending-index fold
                    int   j = ip[k];
                    float v = vp[k];
                    const float* srw = Sl + (size_t)j * CODE_DIM + colb;
                    #pragma unroll
                    for (int ns = 0; ns < 8; ++ns)
                        za[ns] = fmaf(v, srw[ns * 16], za[ns]);
                }
                if (store_za) {                           // exact za for refine
                    float* zap = za_row(zaA, zaB, zaC, row);
                    #pragma unroll
                    for (int ns = 0; ns < 8; ++ns)
                        zap[colb + ns * 16] = za[ns];
                }
                #pragma unroll
                for (int ns = 0; ns < 8; ++ns) acc[mr][ns][q] += za[ns];
            }
        }
    }

    #pragma unroll
    for (int mr = 0; mr < 2; ++mr)
        #pragma unroll
        for (int ns = 0; ns < 8; ++ns)
            #pragma unroll
            for (int q = 0; q < 4; ++q) {
                const int row = r0 + w * 32 + mr * 16 + g * 4 + q;
                u[(size_t)row * CODE_DIM + c0 + ns * 16 + m16] = f2bf(acc[mr][ns][q]);
            }
}

// ---------------------------------------------------------------------------
// top-NCAND candidate SET by |bf16 screen u| (one wave per row).
__global__ __launch_bounds__(256) void topk40_kernel(const unsigned short* __restrict__ u,
                                                     int* __restrict__ cidx)
{
    const int lane = threadIdx.x & 63;
    const int row  = blockIdx.x * 4 + (threadIdx.x >> 6);
    const unsigned short* ur = u + (size_t)row * CODE_DIM;

    uint32_t a[32];
    #pragma unroll
    for (int q = 0; q < 4; ++q) {
        uint4 v = *(const uint4*)&ur[lane * 32 + q * 8];
        a[q * 8 + 0] = (v.x & 0x7fffu) + 1u;
        a[q * 8 + 1] = ((v.x >> 16) & 0x7fffu) + 1u;
        a[q * 8 + 2] = (v.y & 0x7fffu) + 1u;
        a[q * 8 + 3] = ((v.y >> 16) & 0x7fffu) + 1u;
        a[q * 8 + 4] = (v.z & 0x7fffu) + 1u;
        a[q * 8 + 5] = ((v.z >> 16) & 0x7fffu) + 1u;
        a[q * 8 + 6] = (v.w & 0x7fffu) + 1u;
        a[q * 8 + 7] = ((v.w >> 16) & 0x7fffu) + 1u;
    }

    uint32_t wi = 0xFFFFFFFFu;
    for (int it = 0; it < NCAND; ++it) {
        uint32_t t0[16], t1[8], t2[4], t3[2];
        #pragma unroll
        for (int j = 0; j < 16; ++j) t0[j] = a[2*j]  > a[2*j+1]  ? a[2*j]  : a[2*j+1];
        #pragma unroll
        for (int j = 0; j < 8;  ++j) t1[j] = t0[2*j] > t0[2*j+1] ? t0[2*j] : t0[2*j+1];
        #pragma unroll
        for (int j = 0; j < 4;  ++j) t2[j] = t1[2*j] > t1[2*j+1] ? t1[2*j] : t1[2*j+1];
        #pragma unroll
        for (int j = 0; j < 2;  ++j) t3[j] = t2[2*j] > t2[2*j+1] ? t2[2*j] : t2[2*j+1];
        const uint32_t mloc = t3[0] > t3[1] ? t3[0] : t3[1];

        uint32_t gmax = mloc;
        #pragma unroll
        for (int off = 1; off <= 32; off <<= 1) {
            uint32_t og = __shfl_xor(gmax, off);
            gmax = og > gmax ? og : gmax;
        }

        unsigned long long bal = __ballot(mloc == gmax);
        int owner = __ffsll(bal) - 1;

        int bj = 0;
        #pragma unroll
        for (int j = 31; j >= 0; --j)
            if (a[j] == gmax) bj = j;
        int bjo = __shfl(bj, owner);

        uint32_t gidx = (uint32_t)owner * 32u + (uint32_t)bjo;
        if (lane == it) wi = gidx;

        if (lane == owner) {
            #pragma unroll
            for (int j = 0; j < 32; ++j)
                if (j == bjo) a[j] = 0u;
        }
    }

    if (lane < NCAND) cidx[(size_t)row * NCAND + lane] = (int)wi;
}

// ---------------------------------------------------------------------------
// REFINE (za path): exact xW chain + single add of the stored exact za.
// Chain bitwise-identical to the full-f32 path (validated r4-r19).
__global__ __launch_bounds__(256) void refine_za_kernel(
    const float* __restrict__ x, const float* __restrict__ WT,
    float* zaA, float* zaB, float* zaC, const int* __restrict__ cidx,
    int* __restrict__ zidx, float* __restrict__ zval, int has_sparse)
{
    __shared__ float xs[4][INPUT_DIM];

    const int t    = threadIdx.x;
    const int lane = t & 63;
    const int w    = t >> 6;
    const int row  = blockIdx.x * 4 + w;

    const float* xr = x + (size_t)row * INPUT_DIM;
    #pragma unroll
    for (int i = 0; i < 2; ++i)
        *(float4*)&xs[w][(lane + i * 64) * 4] = *(const float4*)&xr[(lane + i * 64) * 4];
    __syncthreads();

    int   c = 0x7fffffff;
    float a = 0.f;
    if (lane < NCAND) {
        c = cidx[(size_t)row * NCAND + lane];
        const float* wc = WT + (size_t)c * INPUT_DIM;
        #pragma unroll 8
        for (int kq = 0; kq < INPUT_DIM / 4; ++kq) {       // k strictly ascending
            float4 wv = *(const float4*)&wc[kq * 4];
            float4 xv = *(const float4*)&xs[w][kq * 4];
            a = fmaf(xv.x, wv.x, a);
            a = fmaf(xv.y, wv.y, a);
            a = fmaf(xv.z, wv.z, a);
            a = fmaf(xv.w, wv.w, a);
        }
        if (has_sparse) {
            const float* zap = za_row(zaA, zaB, zaC, row);
            a = a + zap[c];                                // single add: u = xw + zs
        }
    }

    uint32_t key = (lane < NCAND) ? ((__float_as_uint(a) & 0x7fffffffu) + 1u) : 0u;

    uint32_t wi = 0u;
    for (int it = 0; it < KSP; ++it) {
        uint32_t bk = key;
        uint32_t bc = (key != 0u) ? (uint32_t)c : 0x7fffffffu;
        #pragma unroll
        for (int off = 1; off <= 32; off <<= 1) {
            uint32_t ok = (uint32_t)__shfl_xor((int)bk, off);
            uint32_t oc = (uint32_t)__shfl_xor((int)bc, off);
            if (ok > bk || (ok == bk && oc < bc)) { bk = ok; bc = oc; }
        }
        if (lane == it) wi = bc;
        if (key != 0u && (uint32_t)c == bc) key = 0u;
    }

    float va = 0.f;
    #pragma unroll
    for (int m = 0; m < NCAND; ++m) {
        uint32_t cm = (uint32_t)__shfl(c, m);
        float    am = __shfl(a, m);
        if (lane < KSP && wi == cm) va = am;
    }

    int rank = 0;
    #pragma unroll
    for (int m = 0; m < KSP; ++m) {
        uint32_t om = (uint32_t)__shfl((int)wi, m);
        rank += (om < wi) ? 1 : 0;
    }
    if (lane < KSP) {
        zidx[(size_t)row * KSP + rank] = (int)wi;
        zval[(size_t)row * KSP + rank] = va;
    }
}

// ---------------------------------------------------------------------------
// REFINE (gather fallback, r19-validated): exact xW + gathered exact zS.
__global__ __launch_bounds__(256) void refine_kernel(
    const float* __restrict__ x, const float* __restrict__ WT,
    const float* __restrict__ Sl, const int* __restrict__ cidx,
    int* __restrict__ zidx, float* __restrict__ zval, int has_sparse)
{
    __shared__ float xs[4][INPUT_DIM];
    __shared__ int   pidx[4][KSP];
    __shared__ float pval[4][KSP];

    const int t    = threadIdx.x;
    const int lane = t & 63;
    const int w    = t >> 6;
    const int row  = blockIdx.x * 4 + w;

    const float* xr = x + (size_t)row * INPUT_DIM;
    #pragma unroll
    for (int i = 0; i < 2; ++i)
        *(float4*)&xs[w][(lane + i * 64) * 4] = *(const float4*)&xr[(lane + i * 64) * 4];
    if (has_sparse && lane < KSP) {
        pidx[w][lane] = zidx[(size_t)row * KSP + lane];
        pval[w][lane] = zval[(size_t)row * KSP + lane];
    }
    __syncthreads();

    int   c = 0x7fffffff;
    float a = 0.f;
    if (lane < NCAND) {
        c = cidx[(size_t)row * NCAND + lane];
        const float* wc = WT + (size_t)c * INPUT_DIM;
        #pragma unroll 8
        for (int kq = 0; kq < INPUT_DIM / 4; ++kq) {
            float4 wv = *(const float4*)&wc[kq * 4];
            float4 xv = *(const float4*)&xs[w][kq * 4];
            a = fmaf(xv.x, wv.x, a);
            a = fmaf(xv.y, wv.y, a);
            a = fmaf(xv.z, wv.z, a);
            a = fmaf(xv.w, wv.w, a);
        }
        if (has_sparse) {
            float za = 0.f;
            #pragma unroll 8
            for (int kk = 0; kk < KSP; ++kk)
                za = fmaf(pval[w][kk], Sl[(size_t)pidx[w][kk] * CODE_DIM + c], za);
            a = a + za;
        }
    }

    uint32_t key = (lane < NCAND) ? ((__float_as_uint(a) & 0x7fffffffu) + 1u) : 0u;

    uint32_t wi = 0u;
    for (int it = 0; it < KSP; ++it) {
        uint32_t bk = key;
        uint32_t bc = (key != 0u) ? (uint32_t)c : 0x7fffffffu;
        #pragma unroll
        for (int off = 1; off <= 32; off <<= 1) {
            uint32_t ok = (uint32_t)__shfl_xor((int)bk, off);
            uint32_t oc = (uint32_t)__shfl_xor((int)bc, off);
            if (ok > bk || (ok == bk && oc < bc)) { bk = ok; bc = oc; }
        }
        if (lane == it) wi = bc;
        if (key != 0u && (uint32_t)c == bc) key = 0u;
    }

    float va = 0.f;
    #pragma unroll
    for (int m = 0; m < NCAND; ++m) {
        uint32_t cm = (uint32_t)__shfl(c, m);
        float    am = __shfl(a, m);
        if (lane < KSP && wi == cm) va = am;
    }

    int rank = 0;
    #pragma unroll
    for (int m = 0; m < KSP; ++m) {
        uint32_t om = (uint32_t)__shfl((int)wi, m);
        rank += (om < wi) ? 1 : 0;
    }
    if (lane < KSP) {
        zidx[(size_t)row * KSP + rank] = (int)wi;
        zval[(size_t)row * KSP + rank] = va;
    }
}

// ---------------------------------------------------------------------------
// FALLBACK (ws too small for everything): r16 f32 gemm (84 VGPR, spill-free)
__global__ __launch_bounds__(256) void gemm_layer_kernel(
    const float* __restrict__ x, const float* __restrict__ Wl,
    const float* __restrict__ Sl, const int* __restrict__ zidx,
    const float* __restrict__ zval, float* __restrict__ u)
{
    __shared__ float As[32][128 + 4];

    const int t   = threadIdx.x;
    const int c0  = blockIdx.x * 128;
    const int r0  = blockIdx.y * 128;
    const int tm0 = (t >> 4) * 8;
    const int cn  = (t & 15) * 4;

    float acc[8][8];
    #pragma unroll
    for (int i = 0; i < 8; ++i)
        #pragma unroll
        for (int j = 0; j < 8; ++j) acc[i][j] = 0.f;

    for (int kt = 0; kt < INPUT_DIM; kt += 32) {
        #pragma unroll
        for (int i = 0; i < 4; ++i) {
            int f   = t * 4 + i;
            int row = f >> 3, kq = f & 7;
            float4 v = *(const float4*)&x[(size_t)(r0 + row) * INPUT_DIM + kt + kq * 4];
            As[kq * 4 + 0][row] = v.x;
            As[kq * 4 + 1][row] = v.y;
            As[kq * 4 + 2][row] = v.z;
            As[kq * 4 + 3][row] = v.w;
        }
        __syncthreads();
        const float* Wb = Wl + (size_t)kt * CODE_DIM + c0 + cn;
        #pragma unroll 4
        for (int kk = 0; kk < 32; ++kk) {
            float av[8], bv[8];
            *(float4*)&av[0] = *(const float4*)&As[kk][tm0];
            *(float4*)&av[4] = *(const float4*)&As[kk][tm0 + 4];
            const float* brow = Wb + (size_t)kk * CODE_DIM;
            *(float4*)&bv[0] = *(const float4*)&brow[0];
            *(float4*)&bv[4] = *(const float4*)&brow[64];
            #pragma unroll
            for (int i = 0; i < 8; ++i)
                #pragma unroll
                for (int j = 0; j < 8; ++j)
                    acc[i][j] = fmaf(av[i], bv[j], acc[i][j]);
        }
        __syncthreads();
    }

    if (Sl != nullptr) {
        #pragma unroll
        for (int i = 0; i < 8; ++i) {
            const int r = r0 + tm0 + i;
            const int*   ip = zidx + (size_t)r * KSP;
            const float* vp = zval + (size_t)r * KSP;
            float zacc[8];
            #pragma unroll
            for (int j = 0; j < 8; ++j) zacc[j] = 0.f;
            for (int k = 0; k < KSP; ++k) {
                int   j = ip[k];
                float v = vp[k];
                const float* srow = Sl + (size_t)j * CODE_DIM + c0 + cn;
                float4 s0 = *(const float4*)&srow[0];
                float4 s1 = *(const float4*)&srow[64];
                zacc[0] = fmaf(v, s0.x, zacc[0]);
                zacc[1] = fmaf(v, s0.y, zacc[1]);
                zacc[2] = fmaf(v, s0.z, zacc[2]);
                zacc[3] = fmaf(v, s0.w, zacc[3]);
                zacc[4] = fmaf(v, s1.x, zacc[4]);
                zacc[5] = fmaf(v, s1.y, zacc[5]);
                zacc[6] = fmaf(v, s1.z, zacc[6]);
                zacc[7] = fmaf(v, s1.w, zacc[7]);
            }
            #pragma unroll
            for (int j = 0; j < 8; ++j)
                acc[i][j] = acc[i][j] + zacc[j];
        }
    }

    #pragma unroll
    for (int i = 0; i < 8; ++i) {
        float* up = u + (size_t)(r0 + tm0 + i) * CODE_DIM + c0 + cn;
        *(float4*)&up[0]  = make_float4(acc[i][0], acc[i][1], acc[i][2], acc[i][3]);
        *(float4*)&up[64] = make_float4(acc[i][4], acc[i][5], acc[i][6], acc[i][7]);
    }
}

// ---------------------------------------------------------------------------
// FALLBACK top-32 on f32 u (exact, index-sorted output) — r12 kernel
__global__ __launch_bounds__(256) void topk32_wave_kernel(const float* __restrict__ u,
                                                          int* __restrict__ zidx,
                                                          float* __restrict__ zval)
{
    const int lane = threadIdx.x & 63;
    const int row  = blockIdx.x * 4 + (threadIdx.x >> 6);
    const float* ur = u + (size_t)row * CODE_DIM;

    uint32_t a[32];
    #pragma unroll
    for (int q = 0; q < 8; ++q) {
        float4 v = *(const float4*)&ur[lane * 32 + q * 4];
        a[q * 4 + 0] = (__float_as_uint(v.x) & 0x7fffffffu) + 1u;
        a[q * 4 + 1] = (__float_as_uint(v.y) & 0x7fffffffu) + 1u;
        a[q * 4 + 2] = (__float_as_uint(v.z) & 0x7fffffffu) + 1u;
        a[q * 4 + 3] = (__float_as_uint(v.w) & 0x7fffffffu) + 1u;
    }

    uint32_t wi = 0xFFFFFFFFu;
    for (int it = 0; it < KSP; ++it) {
        uint32_t t0[16], t1[8], t2[4], t3[2];
        #pragma unroll
        for (int j = 0; j < 16; ++j) t0[j] = a[2*j]  > a[2*j+1]  ? a[2*j]  : a[2*j+1];
        #pragma unroll
        for (int j = 0; j < 8;  ++j) t1[j] = t0[2*j] > t0[2*j+1] ? t0[2*j] : t0[2*j+1];
        #pragma unroll
        for (int j = 0; j < 4;  ++j) t2[j] = t1[2*j] > t1[2*j+1] ? t1[2*j] : t1[2*j+1];
        #pragma unroll
        for (int j = 0; j < 2;  ++j) t3[j] = t2[2*j] > t2[2*j+1] ? t2[2*j] : t2[2*j+1];
        const uint32_t mloc = t3[0] > t3[1] ? t3[0] : t3[1];

        uint32_t g = mloc;
        #pragma unroll
        for (int off = 1; off <= 32; off <<= 1) {
            uint32_t og = __shfl_xor(g, off);
            g = og > g ? og : g;
        }
        unsigned long long bal = __ballot(mloc == g);
        int owner = __ffsll(bal) - 1;
        int bj = 0;
        #pragma unroll
        for (int j = 31; j >= 0; --j)
            if (a[j] == g) bj = j;
        int bjo = __shfl(bj, owner);
        uint32_t gidx = (uint32_t)owner * 32u + (uint32_t)bjo;
        if (lane == it) wi = gidx;
        if (lane == owner) {
            #pragma unroll
            for (int j = 0; j < 32; ++j)
                if (j == bjo) a[j] = 0u;
        }
    }

    int rank = 0;
    #pragma unroll
    for (int m = 0; m < 32; ++m) {
        uint32_t om = __shfl(wi, m);
        rank += (om < wi) ? 1 : 0;
    }
    if (lane < KSP) {
        int idx = (int)wi;
        zidx[(size_t)row * KSP + rank] = idx;
        zval[(size_t)row * KSP + rank] = ur[idx];
    }
}

// ---------------------------------------------------------------------------
__global__ __launch_bounds__(256) void zfill_scatter_kernel(const int* __restrict__ zidx,
                                                            const float* __restrict__ zval,
                                                            float* __restrict__ zden)
{
    const int t  = threadIdx.x;
    const int r0 = blockIdx.x * 8;
    float* base = zden + (size_t)r0 * CODE_DIM;
    const float4 zero = make_float4(0.f, 0.f, 0.f, 0.f);
    for (int q = t; q < 8 * CODE_DIM / 4; q += 256)
        *(float4*)&base[q * 4] = zero;
    __syncthreads();
    const int rl = t >> 5, k = t & 31;
    int   idx = zidx[(size_t)(r0 + rl) * KSP + k];
    float v   = zval[(size_t)(r0 + rl) * KSP + k];
    base[(size_t)rl * CODE_DIM + idx] = v;
}

// ---------------------------------------------------------------------------
__global__ __launch_bounds__(128) void recon_kernel(const int* __restrict__ zidx,
                                                    const float* __restrict__ zval,
                                                    const float* __restrict__ Dt,
                                                    float* __restrict__ recon)
{
    const int t   = threadIdx.x;
    const int row = blockIdx.x;
    float4 acc = make_float4(0.f, 0.f, 0.f, 0.f);
    const int*   ip = zidx + (size_t)row * KSP;
    const float* vp = zval + (size_t)row * KSP;
    for (int k = 0; k < KSP; ++k) {
        int   j = ip[k];
        float v = vp[k];
        float4 d = *(const float4*)&Dt[(size_t)j * INPUT_DIM + t * 4];
        acc.x = fmaf(v, d.x, acc.x);
        acc.y = fmaf(v, d.y, acc.y);
        acc.z = fmaf(v, d.z, acc.z);
        acc.w = fmaf(v, d.w, acc.w);
    }
    *(float4*)&recon[(size_t)row * INPUT_DIM + t * 4] = acc;
}

// ---------------------------------------------------------------------------
extern "C" void kernel_launch(void* const* d_in, const int* in_sizes, int n_in,
                              void* d_out, int out_size, void* d_ws, size_t ws_size,
                              hipStream_t stream)
{
    const float* x = (const float*)d_in[0];
    const float* W = (const float*)d_in[1];   // [5][512][2048]
    const float* S = (const float*)d_in[2];   // [5][2048][2048]
    const float* D = (const float*)d_in[3];   // [512][2048]

    float* recon = (float*)d_out;
    float* zden  = (float*)d_out + (size_t)BATCH * INPUT_DIM;  // u scratch, then dense z
    unsigned short* ub = (unsigned short*)zden;                // bf16 u (fast paths)

    char* p = (char*)d_ws;
    int*            zidx = (int*)p;            p += (size_t)BATCH * KSP * 4;
    float*          zval = (float*)p;          p += (size_t)BATCH * KSP * 4;
    float*          Dt   = (float*)p;          p += (size_t)CODE_DIM * INPUT_DIM * 4;
    int*            cidx = (int*)p;            p += (size_t)BATCH * NCAND * 4;
    float*          WT   = (float*)p;          p += (size_t)CODE_DIM * INPUT_DIM * 4;
    unsigned short* WbT  = (unsigned short*)p; p += (size_t)CODE_DIM * INPUT_DIM * 2;
    unsigned short* xb   = (unsigned short*)p; p += (size_t)BATCH * INPUT_DIM * 2;
    const size_t need_mid = (size_t)(p - (char*)d_ws);
    float*          zaC  = (float*)p;          p += (size_t)8192 * CODE_DIM * 4;     // 67 MB
    const size_t need_za = (size_t)(p - (char*)d_ws);

    const bool fast = ws_size >= need_mid;
    const bool use_za = ws_size >= need_za;

    // za region split (rows): A = zden second half (16384), B = recon (8192), C = ws (8192)
    float* zaA = (float*)((char*)zden + (size_t)BATCH * CODE_DIM * 2);  // after bf16 u
    float* zaB = recon;

    transpose_512x2048_kernel<<<dim3(CODE_DIM / 32, INPUT_DIM / 32), dim3(32, 8), 0, stream>>>(D, Dt);

    if (fast) {
        cvt_x_kernel<<<BATCH * INPUT_DIM / (256 * 8), 256, 0, stream>>>(x, xb);
        for (int l = 0; l < LAYERS; ++l) {
            const float* Wl = W + (size_t)l * INPUT_DIM * CODE_DIM;
            const float* Sl = (l == 0) ? nullptr : S + (size_t)l * CODE_DIM * CODE_DIM;
            wt_dual_kernel<<<dim3(CODE_DIM / 32, INPUT_DIM / 32), dim3(32, 8), 0, stream>>>(Wl, WT, WbT);
            screen_kernel<<<dim3(CODE_DIM / 128, BATCH / 128), 256, 0, stream>>>(
                xb, WbT, Sl, (l == 0) ? nullptr : zidx, (l == 0) ? nullptr : zval, ub,
                zaA, zaB, zaC, use_za ? 1 : 0);
            topk40_kernel<<<BATCH / 4, 256, 0, stream>>>(ub, cidx);
            if (use_za)
                refine_za_kernel<<<BATCH / 4, 256, 0, stream>>>(
                    x, WT, zaA, zaB, zaC, cidx, zidx, zval, l > 0 ? 1 : 0);
            else
                refine_kernel<<<BATCH / 4, 256, 0, stream>>>(
                    x, WT, Sl, cidx, zidx, zval, l > 0 ? 1 : 0);
        }
    } else {
        for (int l = 0; l < LAYERS; ++l) {
            const float* Wl = W + (size_t)l * INPUT_DIM * CODE_DIM;
            const float* Sl = (l == 0) ? nullptr : S + (size_t)l * CODE_DIM * CODE_DIM;
            gemm_layer_kernel<<<dim3(CODE_DIM / 128, BATCH / 128), 256, 0, stream>>>(
                x, Wl, Sl, (l == 0) ? nullptr : zidx, (l == 0) ? nullptr : zval, zden);
            topk32_wave_kernel<<<BATCH / 4, 256, 0, stream>>>(zden, zidx, zval);
        }
    }

    zfill_scatter_kernel<<<BATCH / 8, 256, 0, stream>>>(zidx, zval, zden);
    recon_kernel<<<BATCH, 128, 0, stream>>>(zidx, zval, Dt, recon);
}